// Round 2
// baseline (9829.742 us; speedup 1.0000x reference)
//
#include <hip/hip_runtime.h>
#include <cstdint>
#include <cmath>

typedef short bf16x8 __attribute__((ext_vector_type(8)));
typedef float f32x4 __attribute__((ext_vector_type(4)));

__device__ inline float b2f(unsigned short u) {
    union { unsigned int i; float f; } c; c.i = ((unsigned int)u) << 16; return c.f;
}
__device__ inline unsigned short f2b(float f) {
    unsigned int x = __float_as_uint(f);
    unsigned int r = x + 0x7fffu + ((x >> 16) & 1u);
    return (unsigned short)(r >> 16);
}
__device__ inline void unpack8(const uint4& u, f32x4& a, f32x4& b) {
    a[0] = __uint_as_float(u.x << 16); a[1] = __uint_as_float(u.x & 0xffff0000u);
    a[2] = __uint_as_float(u.y << 16); a[3] = __uint_as_float(u.y & 0xffff0000u);
    b[0] = __uint_as_float(u.z << 16); b[1] = __uint_as_float(u.z & 0xffff0000u);
    b[2] = __uint_as_float(u.w << 16); b[3] = __uint_as_float(u.w & 0xffff0000u);
}

// ---------------- weight transpose+cast: W[K][N] (f32) -> Wt[N][K] (bf16) ----------------
__global__ __launch_bounds__(256) void transpose_f32_to_bf16(
    const float* __restrict__ W, unsigned short* __restrict__ Wt, int K, int N)
{
    __shared__ unsigned short sh[32][33];
    int n0 = blockIdx.x * 32;
    int k0 = blockIdx.y * 32;
    int tr = threadIdx.x >> 5;   // 0..7
    int tc = threadIdx.x & 31;   // 0..31
#pragma unroll
    for (int i = 0; i < 4; i++)
        sh[tr + i * 8][tc] = f2b(W[(size_t)(k0 + tr + i * 8) * N + n0 + tc]);
    __syncthreads();
#pragma unroll
    for (int i = 0; i < 4; i++)
        Wt[(size_t)(n0 + tr + i * 8) * K + k0 + tc] = sh[tc][tr + i * 8];
}

// ---------------- fp32 copy (8 elems/thread) ----------------
__global__ __launch_bounds__(256) void copy_f32(const float* __restrict__ in,
                                                float* __restrict__ out)
{
    size_t i = ((size_t)blockIdx.x * 256 + threadIdx.x) * 8;
    f32x4 a = *(const f32x4*)(in + i);
    f32x4 b = *(const f32x4*)(in + i + 4);
    *(f32x4*)(out + i) = a;
    *(f32x4*)(out + i + 4) = b;
}

// ---------------- layernorm: fp32 in -> bf16 out ----------------
__global__ __launch_bounds__(256) void layernorm_k(
    const float* __restrict__ x, const float* __restrict__ gamma,
    const float* __restrict__ beta, unsigned short* __restrict__ out)
{
    int row = blockIdx.x;
    int t = threadIdx.x;
    f32x4 v = *(const f32x4*)(x + (size_t)row * 1024 + t * 4);
    float s  = v[0] + v[1] + v[2] + v[3];
    float s2 = v[0]*v[0] + v[1]*v[1] + v[2]*v[2] + v[3]*v[3];
#pragma unroll
    for (int off = 32; off >= 1; off >>= 1) {
        s  += __shfl_xor(s,  off);
        s2 += __shfl_xor(s2, off);
    }
    __shared__ float red[8];
    int w = t >> 6;
    if ((t & 63) == 0) { red[w] = s; red[4 + w] = s2; }
    __syncthreads();
    s  = red[0] + red[1] + red[2] + red[3];
    s2 = red[4] + red[5] + red[6] + red[7];
    float mu  = s * (1.f / 1024.f);
    float var = s2 * (1.f / 1024.f) - mu * mu;
    float rs  = rsqrtf(var + 1e-5f);
    int c = t * 4;
    f32x4 g = *(const f32x4*)(gamma + c);
    f32x4 be = *(const f32x4*)(beta + c);
    unsigned int lo, hi;
    {
        float o0 = (v[0] - mu) * rs * g[0] + be[0];
        float o1 = (v[1] - mu) * rs * g[1] + be[1];
        float o2 = (v[2] - mu) * rs * g[2] + be[2];
        float o3 = (v[3] - mu) * rs * g[3] + be[3];
        lo = (unsigned)f2b(o0) | ((unsigned)f2b(o1) << 16);
        hi = (unsigned)f2b(o2) | ((unsigned)f2b(o3) << 16);
    }
    uint2 pk; pk.x = lo; pk.y = hi;
    *(uint2*)(out + (size_t)row * 1024 + c) = pk;
}

// ---------------- MFMA GEMM: C[M][N] = A[M][K](bf16) * Bt[N][K]^T(bf16) + bias(f32) ----------------
// MODE 0: bf16 out = v + bias
// MODE 1: bf16 out = gelu_exact(v + bias)
// MODE 2: f32 out[gr*N+gc] += v + bias  (residual add)
template<int MODE>
__global__ __launch_bounds__(256) void gemm_bt(
    const unsigned short* __restrict__ A,
    const unsigned short* __restrict__ Bt,
    const float* __restrict__ bias,
    void* __restrict__ outp,
    int M, int N, int K)
{
    __shared__ unsigned short As[128 * 40];
    __shared__ unsigned short Bs[128 * 40];
    const int t = threadIdx.x;
    const int n0 = blockIdx.x * 128;
    const int m0 = blockIdx.y * 128;
    const int lane = t & 63;
    const int wave = t >> 6;
    const int wm = (wave >> 1) * 64;
    const int wn = (wave & 1) * 64;
    const int lm = lane & 15;
    const int q  = lane >> 4;

    f32x4 acc[4][4];
#pragma unroll
    for (int i = 0; i < 4; i++)
#pragma unroll
        for (int n = 0; n < 4; n++) acc[i][n] = (f32x4)0.f;

    for (int k0 = 0; k0 < K; k0 += 32) {
        __syncthreads();
#pragma unroll
        for (int p = 0; p < 2; p++) {
            int idx = p * 256 + t;          // 0..511
            int row = idx >> 2;             // 0..127
            int cg  = (idx & 3) << 3;       // 0,8,16,24
            uint4 va = *(const uint4*)(A  + (size_t)(m0 + row) * K + k0 + cg);
            *(uint4*)(As + row * 40 + cg) = va;
            uint4 vb = *(const uint4*)(Bt + (size_t)(n0 + row) * K + k0 + cg);
            *(uint4*)(Bs + row * 40 + cg) = vb;
        }
        __syncthreads();
        bf16x8 af[4], bfr[4];
#pragma unroll
        for (int i = 0; i < 4; i++)
            af[i] = *(const bf16x8*)(As + (wm + i * 16 + lm) * 40 + q * 8);
#pragma unroll
        for (int n = 0; n < 4; n++)
            bfr[n] = *(const bf16x8*)(Bs + (wn + n * 16 + lm) * 40 + q * 8);
#pragma unroll
        for (int i = 0; i < 4; i++)
#pragma unroll
            for (int n = 0; n < 4; n++)
                acc[i][n] = __builtin_amdgcn_mfma_f32_16x16x32_bf16(af[i], bfr[n], acc[i][n], 0, 0, 0);
    }

    // epilogue: D row = q*4 + r, col = lm (within each 16x16 tile)
#pragma unroll
    for (int i = 0; i < 4; i++) {
#pragma unroll
        for (int n = 0; n < 4; n++) {
            int gc = n0 + wn + n * 16 + lm;
            float bv = bias[gc];
#pragma unroll
            for (int r = 0; r < 4; r++) {
                int gr = m0 + wm + i * 16 + q * 4 + r;
                float v = acc[i][n][r] + bv;
                if (MODE == 0) {
                    ((unsigned short*)outp)[(size_t)gr * N + gc] = f2b(v);
                } else if (MODE == 1) {
                    float g = 0.5f * v * (1.f + erff(v * 0.70710678118654752f));
                    ((unsigned short*)outp)[(size_t)gr * N + gc] = f2b(g);
                } else {
                    ((float*)outp)[(size_t)gr * N + gc] += v;
                }
            }
        }
    }
}

// ---------------- flash attention (fp32 VALU), adds into residual ----------------
// grid = 2048: blk = ((b*16 + h)*16 + qt); 64 q-rows per block; 16 heads, hd=64
__global__ __launch_bounds__(256) void attn_k(
    const unsigned short* __restrict__ qb,
    const unsigned short* __restrict__ kb,
    const unsigned short* __restrict__ vb,
    float* __restrict__ x)
{
    constexpr int PAD = 68;
    __shared__ float Ks[64 * PAD];
    __shared__ float Vs[64 * PAD];
    __shared__ float Ss[64 * PAD];
    const int t   = threadIdx.x;
    const int blk = blockIdx.x;
    const int qt  = blk & 15;
    const int h   = (blk >> 4) & 15;
    const int b   = blk >> 8;
    const int r   = t >> 2;          // q-row within tile
    const int cg  = (t & 3) << 4;    // 16-wide column group

    const size_t qrow = ((size_t)(b * 1024 + qt * 64 + r)) * 1024 + h * 64;

    // Q row -> registers (fp32), 64 elems
    f32x4 qreg[16];
    {
        const uint4* src = (const uint4*)(qb + qrow);
#pragma unroll
        for (int j = 0; j < 8; j++) {
            uint4 u = src[j];
            f32x4 a, c; unpack8(u, a, c);
            qreg[2 * j] = a; qreg[2 * j + 1] = c;
        }
    }

    float m_r = -1e30f, l_r = 0.f;
    f32x4 O[4];
#pragma unroll
    for (int j = 0; j < 4; j++) O[j] = (f32x4)0.f;

    for (int kt = 0; kt < 16; ++kt) {
        __syncthreads();
        {
            size_t base = ((size_t)(b * 1024 + kt * 64 + r)) * 1024 + h * 64 + cg;
            const uint4* kp = (const uint4*)(kb + base);
            const uint4* vp = (const uint4*)(vb + base);
            uint4 k1 = kp[0], k2 = kp[1];
            uint4 v1 = vp[0], v2 = vp[1];
            f32x4 a, c;
            unpack8(k1, a, c);
            *(f32x4*)&Ks[r * PAD + cg]      = a;
            *(f32x4*)&Ks[r * PAD + cg + 4]  = c;
            unpack8(k2, a, c);
            *(f32x4*)&Ks[r * PAD + cg + 8]  = a;
            *(f32x4*)&Ks[r * PAD + cg + 12] = c;
            unpack8(v1, a, c);
            *(f32x4*)&Vs[r * PAD + cg]      = a;
            *(f32x4*)&Vs[r * PAD + cg + 4]  = c;
            unpack8(v2, a, c);
            *(f32x4*)&Vs[r * PAD + cg + 8]  = a;
            *(f32x4*)&Vs[r * PAD + cg + 12] = c;
        }
        __syncthreads();

        // S = q . k for this thread's 16 keys (cg..cg+15), scaled by 1/32
        float sacc[16];
#pragma unroll
        for (int kk = 0; kk < 16; kk++) {
            const f32x4* kp = (const f32x4*)&Ks[(cg + kk) * PAD];
            float s = 0.f;
#pragma unroll
            for (int d = 0; d < 16; d++) {
                f32x4 kv = kp[d];
                s += qreg[d][0] * kv[0] + qreg[d][1] * kv[1]
                   + qreg[d][2] * kv[2] + qreg[d][3] * kv[3];
            }
            sacc[kk] = s * 0.03125f;
        }

        // online softmax over the 4-lane group sharing row r
        float tm = sacc[0];
#pragma unroll
        for (int j = 1; j < 16; j++) tm = fmaxf(tm, sacc[j]);
        tm = fmaxf(tm, __shfl_xor(tm, 1));
        tm = fmaxf(tm, __shfl_xor(tm, 2));
        float nm = fmaxf(m_r, tm);
        float alpha = __expf(m_r - nm);
        float ls = 0.f;
#pragma unroll
        for (int j = 0; j < 16; j++) {
            float p = __expf(sacc[j] - nm);
            Ss[r * PAD + cg + j] = p;
            ls += p;
        }
        ls += __shfl_xor(ls, 1);
        ls += __shfl_xor(ls, 2);
        l_r = l_r * alpha + ls;
        m_r = nm;
#pragma unroll
        for (int j = 0; j < 4; j++) O[j] *= alpha;
        __syncthreads();

        // O += P * V
        for (int k = 0; k < 64; k++) {
            float pk = Ss[r * PAD + k];
            const f32x4* vp = (const f32x4*)&Vs[k * PAD + cg];
            O[0] += pk * vp[0];
            O[1] += pk * vp[1];
            O[2] += pk * vp[2];
            O[3] += pk * vp[3];
        }
    }

    float inv = 1.f / l_r;
    float* xp = x + qrow + cg;
#pragma unroll
    for (int j = 0; j < 4; j++) {
        f32x4 xv = *(f32x4*)(xp + j * 4);
        xv += O[j] * inv;
        *(f32x4*)(xp + j * 4) = xv;
    }
}

// ---------------- launch ----------------
extern "C" void kernel_launch(void* const* d_in, const int* in_sizes, int n_in,
                              void* d_out, int out_size, void* d_ws, size_t ws_size,
                              hipStream_t stream)
{
    (void)in_sizes; (void)n_in; (void)out_size; (void)ws_size;
    const float* x_in  = (const float*)d_in[0];
    const float* Wq    = (const float*)d_in[1];
    const float* bq    = (const float*)d_in[2];
    const float* Wk    = (const float*)d_in[3];
    const float* bk    = (const float*)d_in[4];
    const float* Wv    = (const float*)d_in[5];
    const float* bv    = (const float*)d_in[6];
    const float* W1    = (const float*)d_in[7];
    const float* b1    = (const float*)d_in[8];
    const float* W2    = (const float*)d_in[9];
    const float* b2    = (const float*)d_in[10];
    const float* gamma = (const float*)d_in[11];
    const float* beta  = (const float*)d_in[12];

    char* base = (char*)d_ws;
    float*          xf   = (float*)(base);                               // 32 MB
    unsigned short* xn   = (unsigned short*)(base + 33554432);           // 16 MB
    // union region: q/k/v (48 MB) overlaps h1 (64 MB) — disjoint lifetimes
    unsigned short* qbuf = (unsigned short*)(base + 50331648);
    unsigned short* kbuf = (unsigned short*)(base + 50331648 + 16777216);
    unsigned short* vbuf = (unsigned short*)(base + 50331648 + 33554432);
    unsigned short* h1   = (unsigned short*)(base + 50331648);           // 64 MB
    char* wbase = base + 50331648 + 67108864;
    unsigned short* WqT = (unsigned short*)(wbase);                      // 2 MB
    unsigned short* WkT = (unsigned short*)(wbase + 2097152);
    unsigned short* WvT = (unsigned short*)(wbase + 4194304);
    unsigned short* W1T = (unsigned short*)(wbase + 6291456);            // 8 MB
    unsigned short* W2T = (unsigned short*)(wbase + 14680064);           // 8 MB

    // once per launch: weight transposes (f32 -> bf16 [N][K]) + residual copy
    transpose_f32_to_bf16<<<dim3(32, 32),  256, 0, stream>>>(Wq, WqT, 1024, 1024);
    transpose_f32_to_bf16<<<dim3(32, 32),  256, 0, stream>>>(Wk, WkT, 1024, 1024);
    transpose_f32_to_bf16<<<dim3(32, 32),  256, 0, stream>>>(Wv, WvT, 1024, 1024);
    transpose_f32_to_bf16<<<dim3(128, 32), 256, 0, stream>>>(W1, W1T, 1024, 4096);
    transpose_f32_to_bf16<<<dim3(32, 128), 256, 0, stream>>>(W2, W2T, 4096, 1024);
    copy_f32<<<4096, 256, 0, stream>>>(x_in, xf);

    for (int layer = 0; layer < 6; ++layer) {
        layernorm_k<<<8192, 256, 0, stream>>>(xf, gamma, beta, xn);
        gemm_bt<0><<<dim3(8, 64),  256, 0, stream>>>(xn, WqT, bq, qbuf, 8192, 1024, 1024);
        gemm_bt<0><<<dim3(8, 64),  256, 0, stream>>>(xn, WkT, bk, kbuf, 8192, 1024, 1024);
        gemm_bt<0><<<dim3(8, 64),  256, 0, stream>>>(xn, WvT, bv, vbuf, 8192, 1024, 1024);
        attn_k<<<2048, 256, 0, stream>>>(qbuf, kbuf, vbuf, xf);
        layernorm_k<<<8192, 256, 0, stream>>>(xf, gamma, beta, xn);
        gemm_bt<1><<<dim3(32, 64), 256, 0, stream>>>(xn, W1T, b1, h1, 8192, 4096, 1024);
        gemm_bt<2><<<dim3(8, 64),  256, 0, stream>>>(h1, W2T, b2, xf, 8192, 1024, 4096);
    }
    copy_f32<<<4096, 256, 0, stream>>>(xf, (float*)d_out);
}

// Round 4
// 3030.940 us; speedup vs baseline: 3.2431x; 3.2431x over previous
//
#include <hip/hip_runtime.h>
#include <cstdint>
#include <cmath>

typedef short bf16x8 __attribute__((ext_vector_type(8)));
typedef float f32x4 __attribute__((ext_vector_type(4)));

__device__ inline float b2f(unsigned short u) {
    union { unsigned int i; float f; } c; c.i = ((unsigned int)u) << 16; return c.f;
}
__device__ inline unsigned short f2b(float f) {
    unsigned int x = __float_as_uint(f);
    unsigned int r = x + 0x7fffu + ((x >> 16) & 1u);
    return (unsigned short)(r >> 16);
}

// ---------------- weight transpose+cast: W[K][N] (f32) -> Wt[N][K] (bf16) ----------------
__global__ __launch_bounds__(256) void transpose_f32_to_bf16(
    const float* __restrict__ W, unsigned short* __restrict__ Wt, int K, int N)
{
    __shared__ unsigned short sh[32][33];
    int n0 = blockIdx.x * 32;
    int k0 = blockIdx.y * 32;
    int tr = threadIdx.x >> 5;   // 0..7
    int tc = threadIdx.x & 31;   // 0..31
#pragma unroll
    for (int i = 0; i < 4; i++)
        sh[tr + i * 8][tc] = f2b(W[(size_t)(k0 + tr + i * 8) * N + n0 + tc]);
    __syncthreads();
#pragma unroll
    for (int i = 0; i < 4; i++)
        Wt[(size_t)(n0 + tr + i * 8) * K + k0 + tc] = sh[tc][tr + i * 8];
}

// ---------------- fp32 copy (8 elems/thread) ----------------
__global__ __launch_bounds__(256) void copy_f32(const float* __restrict__ in,
                                                float* __restrict__ out)
{
    size_t i = ((size_t)blockIdx.x * 256 + threadIdx.x) * 8;
    f32x4 a = *(const f32x4*)(in + i);
    f32x4 b = *(const f32x4*)(in + i + 4);
    *(f32x4*)(out + i) = a;
    *(f32x4*)(out + i + 4) = b;
}

// ---------------- layernorm: fp32 in -> bf16 out ----------------
__global__ __launch_bounds__(256) void layernorm_k(
    const float* __restrict__ x, const float* __restrict__ gamma,
    const float* __restrict__ beta, unsigned short* __restrict__ out)
{
    int row = blockIdx.x;
    int t = threadIdx.x;
    f32x4 v = *(const f32x4*)(x + (size_t)row * 1024 + t * 4);
    float s  = v[0] + v[1] + v[2] + v[3];
    float s2 = v[0]*v[0] + v[1]*v[1] + v[2]*v[2] + v[3]*v[3];
#pragma unroll
    for (int off = 32; off >= 1; off >>= 1) {
        s  += __shfl_xor(s,  off);
        s2 += __shfl_xor(s2, off);
    }
    __shared__ float red[8];
    int w = t >> 6;
    if ((t & 63) == 0) { red[w] = s; red[4 + w] = s2; }
    __syncthreads();
    s  = red[0] + red[1] + red[2] + red[3];
    s2 = red[4] + red[5] + red[6] + red[7];
    float mu  = s * (1.f / 1024.f);
    float var = s2 * (1.f / 1024.f) - mu * mu;
    float rs  = rsqrtf(var + 1e-5f);
    int c = t * 4;
    f32x4 g = *(const f32x4*)(gamma + c);
    f32x4 be = *(const f32x4*)(beta + c);
    unsigned int lo, hi;
    {
        float o0 = (v[0] - mu) * rs * g[0] + be[0];
        float o1 = (v[1] - mu) * rs * g[1] + be[1];
        float o2 = (v[2] - mu) * rs * g[2] + be[2];
        float o3 = (v[3] - mu) * rs * g[3] + be[3];
        lo = (unsigned)f2b(o0) | ((unsigned)f2b(o1) << 16);
        hi = (unsigned)f2b(o2) | ((unsigned)f2b(o3) << 16);
    }
    uint2 pk; pk.x = lo; pk.y = hi;
    *(uint2*)(out + (size_t)row * 1024 + c) = pk;
}

// ---------------- MFMA GEMM: C[M][N] = A[M][K](bf16) * Bt[N][K]^T(bf16) + bias(f32) ----------------
// MODE 0: bf16 out = v + bias
// MODE 1: bf16 out = gelu_exact(v + bias)
// MODE 2: f32 out[gr*N+gc] += v + bias  (residual add)
template<int MODE>
__global__ __launch_bounds__(256) void gemm_bt(
    const unsigned short* __restrict__ A,
    const unsigned short* __restrict__ Bt,
    const float* __restrict__ bias,
    void* __restrict__ outp,
    int M, int N, int K)
{
    __shared__ unsigned short As[128 * 40];
    __shared__ unsigned short Bs[128 * 40];
    const int t = threadIdx.x;
    const int n0 = blockIdx.x * 128;
    const int m0 = blockIdx.y * 128;
    const int lane = t & 63;
    const int wave = t >> 6;
    const int wm = (wave >> 1) * 64;
    const int wn = (wave & 1) * 64;
    const int lm = lane & 15;
    const int q  = lane >> 4;

    f32x4 acc[4][4];
#pragma unroll
    for (int i = 0; i < 4; i++)
#pragma unroll
        for (int n = 0; n < 4; n++) acc[i][n] = (f32x4)0.f;

    for (int k0 = 0; k0 < K; k0 += 32) {
        __syncthreads();
#pragma unroll
        for (int p = 0; p < 2; p++) {
            int idx = p * 256 + t;          // 0..511
            int row = idx >> 2;             // 0..127
            int cg  = (idx & 3) << 3;       // 0,8,16,24
            uint4 va = *(const uint4*)(A  + (size_t)(m0 + row) * K + k0 + cg);
            *(uint4*)(As + row * 40 + cg) = va;
            uint4 vb = *(const uint4*)(Bt + (size_t)(n0 + row) * K + k0 + cg);
            *(uint4*)(Bs + row * 40 + cg) = vb;
        }
        __syncthreads();
        bf16x8 af[4], bfr[4];
#pragma unroll
        for (int i = 0; i < 4; i++)
            af[i] = *(const bf16x8*)(As + (wm + i * 16 + lm) * 40 + q * 8);
#pragma unroll
        for (int n = 0; n < 4; n++)
            bfr[n] = *(const bf16x8*)(Bs + (wn + n * 16 + lm) * 40 + q * 8);
#pragma unroll
        for (int i = 0; i < 4; i++)
#pragma unroll
            for (int n = 0; n < 4; n++)
                acc[i][n] = __builtin_amdgcn_mfma_f32_16x16x32_bf16(af[i], bfr[n], acc[i][n], 0, 0, 0);
    }

    // epilogue: D row = q*4 + r, col = lm (within each 16x16 tile)
#pragma unroll
    for (int i = 0; i < 4; i++) {
#pragma unroll
        for (int n = 0; n < 4; n++) {
            int gc = n0 + wn + n * 16 + lm;
            float bv = bias[gc];
#pragma unroll
            for (int r = 0; r < 4; r++) {
                int gr = m0 + wm + i * 16 + q * 4 + r;
                float v = acc[i][n][r] + bv;
                if (MODE == 0) {
                    ((unsigned short*)outp)[(size_t)gr * N + gc] = f2b(v);
                } else if (MODE == 1) {
                    float g = 0.5f * v * (1.f + erff(v * 0.70710678118654752f));
                    ((unsigned short*)outp)[(size_t)gr * N + gc] = f2b(g);
                } else {
                    ((float*)outp)[(size_t)gr * N + gc] += v;
                }
            }
        }
    }
}

// ---------------- MFMA flash attention, adds into fp32 residual ----------------
// grid = 2048: blk = ((b*16 + h)*16 + qt); 64 q-rows per block, 4 waves x 16 rows.
// Layouts (16x16x32 bf16 MFMA):
//   A-frag: lane holds m = lane&15, k = (lane>>4)*8 + j   (8 contiguous bf16)
//   B-frag: lane holds n = lane&15, k = (lane>>4)*8 + j
//   C:      lane holds col = lane&15, row = (lane>>4)*4 + reg
// Qs/Ks: [row][d], pitch 72 shorts (144 B -> 16B-aligned, banks 2-way max).
// Vst:   [d][key], 8-key (16 B) chunks XOR-swizzled by ((d ^ d>>3) & 7) so both
//        the packed-pair transpose writes and the b128 frag reads are bank-balanced.
__global__ __launch_bounds__(256) void attn_k(
    const unsigned short* __restrict__ qb,
    const unsigned short* __restrict__ kb,
    const unsigned short* __restrict__ vb,
    float* __restrict__ x)
{
    __shared__ unsigned short Qs[64 * 72];
    __shared__ unsigned short Ks[64 * 72];
    __shared__ unsigned short Vst[64 * 64];
    __shared__ unsigned short Ps[4][16 * 72];

    const int t    = threadIdx.x;
    const int blk  = blockIdx.x;
    const int qt   = blk & 15;
    const int h    = (blk >> 4) & 15;
    const int b    = blk >> 8;
    const int w    = t >> 6;
    const int lane = t & 63;
    const int l15  = lane & 15;
    const int quad = lane >> 4;

    // ---- stage Q tile (64 rows x 64 d) ----
    {
        int r  = t >> 2;
        int dc = (t & 3) << 4;
        const uint4* src = (const uint4*)(qb + ((size_t)(b * 1024 + qt * 64 + r)) * 1024 + h * 64 + dc);
        uint4 u0 = src[0], u1 = src[1];
        *(uint4*)(Qs + r * 72 + dc)     = u0;
        *(uint4*)(Qs + r * 72 + dc + 8) = u1;
    }
    __syncthreads();
    bf16x8 qf0 = *(const bf16x8*)(Qs + (w * 16 + l15) * 72 + quad * 8);
    bf16x8 qf1 = *(const bf16x8*)(Qs + (w * 16 + l15) * 72 + 32 + quad * 8);

    float m_r[4], l_r[4];
    f32x4 O[4];
#pragma unroll
    for (int r = 0; r < 4; r++) { m_r[r] = -1e30f; l_r[r] = 0.f; }
#pragma unroll
    for (int n = 0; n < 4; n++) O[n] = (f32x4)0.f;

    for (int kt = 0; kt < 16; ++kt) {
        __syncthreads();
        // ---- stage K tile [key][d] ----
        {
            int r  = t >> 2;
            int dc = (t & 3) << 4;
            const uint4* src = (const uint4*)(kb + ((size_t)(b * 1024 + kt * 64 + r)) * 1024 + h * 64 + dc);
            uint4 u0 = src[0], u1 = src[1];
            *(uint4*)(Ks + r * 72 + dc)     = u0;
            *(uint4*)(Ks + r * 72 + dc + 8) = u1;
        }
        // ---- stage V tile transposed+swizzled [d][key] ----
        {
            int r2  = t >> 3;            // key pair index 0..31
            int dc  = (t & 7) << 3;      // d chunk 0,8,..,56
            const unsigned short* v0 = vb + ((size_t)(b * 1024 + kt * 64 + 2 * r2)) * 1024 + h * 64 + dc;
            uint4 a0 = *(const uint4*)(v0);
            uint4 a1 = *(const uint4*)(v0 + 1024);
            const unsigned short* s0 = (const unsigned short*)&a0;
            const unsigned short* s1 = (const unsigned short*)&a1;
            int dc3 = dc >> 3;
            int lc  = r2 >> 2;           // logical 8-key chunk
            int ko  = (2 * r2) & 7;      // key offset within chunk
#pragma unroll
            for (int j = 0; j < 8; j++) {
                int sw = (j ^ dc3) & 7;
                unsigned int pk = (unsigned int)s0[j] | ((unsigned int)s1[j] << 16);
                *(unsigned int*)(Vst + (dc + j) * 64 + ((lc ^ sw) << 3) + ko) = pk;
            }
        }
        __syncthreads();

        // ---- S = Q K^T (16 q-rows x 64 keys per wave) ----
        f32x4 s[4];
#pragma unroll
        for (int nt = 0; nt < 4; nt++) {
            bf16x8 k0 = *(const bf16x8*)(Ks + (nt * 16 + l15) * 72 + quad * 8);
            bf16x8 k1 = *(const bf16x8*)(Ks + (nt * 16 + l15) * 72 + 32 + quad * 8);
            f32x4 acc = (f32x4)0.f;
            acc = __builtin_amdgcn_mfma_f32_16x16x32_bf16(qf0, k0, acc, 0, 0, 0);
            acc = __builtin_amdgcn_mfma_f32_16x16x32_bf16(qf1, k1, acc, 0, 0, 0);
            s[nt] = acc * 0.03125f;   // SCALE = 1024^-0.5
        }

        // ---- online softmax (rows = quad*4+r; reduce cols via xor-shuffles) ----
#pragma unroll
        for (int r = 0; r < 4; r++) {
            float tm = fmaxf(fmaxf(s[0][r], s[1][r]), fmaxf(s[2][r], s[3][r]));
            tm = fmaxf(tm, __shfl_xor(tm, 1));
            tm = fmaxf(tm, __shfl_xor(tm, 2));
            tm = fmaxf(tm, __shfl_xor(tm, 4));
            tm = fmaxf(tm, __shfl_xor(tm, 8));
            float nm    = fmaxf(m_r[r], tm);
            float alpha = __expf(m_r[r] - nm);
            float ls = 0.f;
#pragma unroll
            for (int nt = 0; nt < 4; nt++) {
                float p = __expf(s[nt][r] - nm);
                s[nt][r] = p;
                ls += p;
            }
            ls += __shfl_xor(ls, 1);
            ls += __shfl_xor(ls, 2);
            ls += __shfl_xor(ls, 4);
            ls += __shfl_xor(ls, 8);
            l_r[r] = l_r[r] * alpha + ls;
            m_r[r] = nm;
            O[0][r] *= alpha; O[1][r] *= alpha; O[2][r] *= alpha; O[3][r] *= alpha;
        }

        // ---- P: C-layout -> A-layout via per-wave LDS round-trip ----
        unsigned short* pw = Ps[w];
#pragma unroll
        for (int nt = 0; nt < 4; nt++)
#pragma unroll
            for (int r = 0; r < 4; r++)
                pw[(quad * 4 + r) * 72 + nt * 16 + l15] = f2b(s[nt][r]);
        bf16x8 pf0 = *(const bf16x8*)(pw + l15 * 72 + quad * 8);
        bf16x8 pf1 = *(const bf16x8*)(pw + l15 * 72 + 32 + quad * 8);

        // ---- O += P V ----
#pragma unroll
        for (int nt = 0; nt < 4; nt++) {
            int d  = nt * 16 + l15;
            int sw = (d ^ (d >> 3)) & 7;
            bf16x8 vf0 = *(const bf16x8*)(Vst + d * 64 + ((quad ^ sw) << 3));
            bf16x8 vf1 = *(const bf16x8*)(Vst + d * 64 + (((4 + quad) ^ sw) << 3));
            O[nt] = __builtin_amdgcn_mfma_f32_16x16x32_bf16(pf0, vf0, O[nt], 0, 0, 0);
            O[nt] = __builtin_amdgcn_mfma_f32_16x16x32_bf16(pf1, vf1, O[nt], 0, 0, 0);
        }
    }

    // ---- epilogue: x += O / l  (C-layout: row = quad*4+r, col = nt*16+l15) ----
    float inv[4];
#pragma unroll
    for (int r = 0; r < 4; r++) inv[r] = 1.f / l_r[r];
#pragma unroll
    for (int nt = 0; nt < 4; nt++) {
#pragma unroll
        for (int r = 0; r < 4; r++) {
            size_t idx = ((size_t)(b * 1024 + qt * 64 + w * 16 + quad * 4 + r)) * 1024
                       + h * 64 + nt * 16 + l15;
            x[idx] += O[nt][r] * inv[r];
        }
    }
}

// ---------------- launch ----------------
extern "C" void kernel_launch(void* const* d_in, const int* in_sizes, int n_in,
                              void* d_out, int out_size, void* d_ws, size_t ws_size,
                              hipStream_t stream)
{
    (void)in_sizes; (void)n_in; (void)out_size; (void)ws_size;
    const float* x_in  = (const float*)d_in[0];
    const float* Wq    = (const float*)d_in[1];
    const float* bq    = (const float*)d_in[2];
    const float* Wk    = (const float*)d_in[3];
    const float* bk    = (const float*)d_in[4];
    const float* Wv    = (const float*)d_in[5];
    const float* bv    = (const float*)d_in[6];
    const float* W1    = (const float*)d_in[7];
    const float* b1    = (const float*)d_in[8];
    const float* W2    = (const float*)d_in[9];
    const float* b2    = (const float*)d_in[10];
    const float* gamma = (const float*)d_in[11];
    const float* beta  = (const float*)d_in[12];

    char* base = (char*)d_ws;
    float*          xf   = (float*)(base);                               // 32 MB
    unsigned short* xn   = (unsigned short*)(base + 33554432);           // 16 MB
    // union region: q/k/v (48 MB) overlaps h1 (64 MB) — disjoint lifetimes
    unsigned short* qbuf = (unsigned short*)(base + 50331648);
    unsigned short* kbuf = (unsigned short*)(base + 50331648 + 16777216);
    unsigned short* vbuf = (unsigned short*)(base + 50331648 + 33554432);
    unsigned short* h1   = (unsigned short*)(base + 50331648);           // 64 MB
    char* wbase = base + 50331648 + 67108864;
    unsigned short* WqT = (unsigned short*)(wbase);                      // 2 MB
    unsigned short* WkT = (unsigned short*)(wbase + 2097152);
    unsigned short* WvT = (unsigned short*)(wbase + 4194304);
    unsigned short* W1T = (unsigned short*)(wbase + 6291456);            // 8 MB
    unsigned short* W2T = (unsigned short*)(wbase + 14680064);           // 8 MB

    // once per launch: weight transposes (f32 -> bf16 [N][K]) + residual copy
    transpose_f32_to_bf16<<<dim3(32, 32),  256, 0, stream>>>(Wq, WqT, 1024, 1024);
    transpose_f32_to_bf16<<<dim3(32, 32),  256, 0, stream>>>(Wk, WkT, 1024, 1024);
    transpose_f32_to_bf16<<<dim3(32, 32),  256, 0, stream>>>(Wv, WvT, 1024, 1024);
    transpose_f32_to_bf16<<<dim3(128, 32), 256, 0, stream>>>(W1, W1T, 1024, 4096);
    transpose_f32_to_bf16<<<dim3(32, 128), 256, 0, stream>>>(W2, W2T, 4096, 1024);
    copy_f32<<<4096, 256, 0, stream>>>(x_in, xf);

    for (int layer = 0; layer < 6; ++layer) {
        layernorm_k<<<8192, 256, 0, stream>>>(xf, gamma, beta, xn);
        gemm_bt<0><<<dim3(8, 64),  256, 0, stream>>>(xn, WqT, bq, qbuf, 8192, 1024, 1024);
        gemm_bt<0><<<dim3(8, 64),  256, 0, stream>>>(xn, WkT, bk, kbuf, 8192, 1024, 1024);
        gemm_bt<0><<<dim3(8, 64),  256, 0, stream>>>(xn, WvT, bv, vbuf, 8192, 1024, 1024);
        attn_k<<<2048, 256, 0, stream>>>(qbuf, kbuf, vbuf, xf);
        layernorm_k<<<8192, 256, 0, stream>>>(xf, gamma, beta, xn);
        gemm_bt<1><<<dim3(32, 64), 256, 0, stream>>>(xn, W1T, b1, h1, 8192, 4096, 1024);
        gemm_bt<2><<<dim3(8, 64),  256, 0, stream>>>(h1, W2T, b2, xf, 8192, 1024, 4096);
    }
    copy_f32<<<4096, 256, 0, stream>>>(xf, (float*)d_out);
}

// Round 5
// 2937.127 us; speedup vs baseline: 3.3467x; 1.0319x over previous
//
#include <hip/hip_runtime.h>
#include <cstdint>
#include <cmath>

typedef short bf16x8 __attribute__((ext_vector_type(8)));
typedef float f32x4 __attribute__((ext_vector_type(4)));

#define AS_GLOBAL(p) (const __attribute__((address_space(1))) void*)(p)
#define AS_LDS(p)    (__attribute__((address_space(3))) void*)(p)

__device__ inline float b2f(unsigned short u) {
    union { unsigned int i; float f; } c; c.i = ((unsigned int)u) << 16; return c.f;
}
__device__ inline unsigned short f2b(float f) {
    unsigned int x = __float_as_uint(f);
    unsigned int r = x + 0x7fffu + ((x >> 16) & 1u);
    return (unsigned short)(r >> 16);
}

// ---------------- weight transpose+cast: W[K][N] (f32) -> Wt[N][K] (bf16) ----------------
__global__ __launch_bounds__(256) void transpose_f32_to_bf16(
    const float* __restrict__ W, unsigned short* __restrict__ Wt, int K, int N)
{
    __shared__ unsigned short sh[32][33];
    int n0 = blockIdx.x * 32;
    int k0 = blockIdx.y * 32;
    int tr = threadIdx.x >> 5;   // 0..7
    int tc = threadIdx.x & 31;   // 0..31
#pragma unroll
    for (int i = 0; i < 4; i++)
        sh[tr + i * 8][tc] = f2b(W[(size_t)(k0 + tr + i * 8) * N + n0 + tc]);
    __syncthreads();
#pragma unroll
    for (int i = 0; i < 4; i++)
        Wt[(size_t)(n0 + tr + i * 8) * K + k0 + tc] = sh[tc][tr + i * 8];
}

// ---------------- fp32 copy (8 elems/thread) ----------------
__global__ __launch_bounds__(256) void copy_f32(const float* __restrict__ in,
                                                float* __restrict__ out)
{
    size_t i = ((size_t)blockIdx.x * 256 + threadIdx.x) * 8;
    f32x4 a = *(const f32x4*)(in + i);
    f32x4 b = *(const f32x4*)(in + i + 4);
    *(f32x4*)(out + i) = a;
    *(f32x4*)(out + i + 4) = b;
}

// ---------------- layernorm: fp32 in -> bf16 out ----------------
__global__ __launch_bounds__(256) void layernorm_k(
    const float* __restrict__ x, const float* __restrict__ gamma,
    const float* __restrict__ beta, unsigned short* __restrict__ out)
{
    int row = blockIdx.x;
    int t = threadIdx.x;
    f32x4 v = *(const f32x4*)(x + (size_t)row * 1024 + t * 4);
    float s  = v[0] + v[1] + v[2] + v[3];
    float s2 = v[0]*v[0] + v[1]*v[1] + v[2]*v[2] + v[3]*v[3];
#pragma unroll
    for (int off = 32; off >= 1; off >>= 1) {
        s  += __shfl_xor(s,  off);
        s2 += __shfl_xor(s2, off);
    }
    __shared__ float red[8];
    int w = t >> 6;
    if ((t & 63) == 0) { red[w] = s; red[4 + w] = s2; }
    __syncthreads();
    s  = red[0] + red[1] + red[2] + red[3];
    s2 = red[4] + red[5] + red[6] + red[7];
    float mu  = s * (1.f / 1024.f);
    float var = s2 * (1.f / 1024.f) - mu * mu;
    float rs  = rsqrtf(var + 1e-5f);
    int c = t * 4;
    f32x4 g = *(const f32x4*)(gamma + c);
    f32x4 be = *(const f32x4*)(beta + c);
    unsigned int lo, hi;
    {
        float o0 = (v[0] - mu) * rs * g[0] + be[0];
        float o1 = (v[1] - mu) * rs * g[1] + be[1];
        float o2 = (v[2] - mu) * rs * g[2] + be[2];
        float o3 = (v[3] - mu) * rs * g[3] + be[3];
        lo = (unsigned)f2b(o0) | ((unsigned)f2b(o1) << 16);
        hi = (unsigned)f2b(o2) | ((unsigned)f2b(o3) << 16);
    }
    uint2 pk; pk.x = lo; pk.y = hi;
    *(uint2*)(out + (size_t)row * 1024 + c) = pk;
}

// ---------------- MFMA GEMM: C[M][N] = A[M][K](bf16) * Bt[N][K]^T(bf16) + bias(f32) ----------------
// m97-style staging: global_load_lds width=16 into unpadded [row][k] pitch-32-short
// tiles. LDS dest = wave-uniform base + lane*16 (HW contract) — lane i of wave w,
// instruction p covers tile position pos = w*128 + p*64 + i; row = pos>>2,
// k-chunk = (pos&3)*8. Fragment reads use the same layout (no pad possible).
// MODE 0: bf16 out = v + bias
// MODE 1: bf16 out = gelu_exact(v + bias)
// MODE 2: f32 out[gr*N+gc] += v + bias  (residual add)
template<int MODE>
__global__ __launch_bounds__(256) void gemm_bt(
    const unsigned short* __restrict__ A,
    const unsigned short* __restrict__ Bt,
    const float* __restrict__ bias,
    void* __restrict__ outp,
    int M, int N, int K)
{
    __shared__ unsigned short As[128 * 32];
    __shared__ unsigned short Bs[128 * 32];
    const int t = threadIdx.x;
    const int n0 = blockIdx.x * 128;
    const int m0 = blockIdx.y * 128;
    const int lane = t & 63;
    const int wave = t >> 6;
    const int wm = (wave >> 1) * 64;
    const int wn = (wave & 1) * 64;
    const int lm = lane & 15;
    const int q  = lane >> 4;

    // staging geometry (per wave, 2 instructions per matrix)
    const int pos0 = wave * 128 + lane;          // + p*64
    const int row0 = pos0 >> 2;                  // rows for p=0
    const int row1 = (pos0 + 64) >> 2;           // rows for p=1
    const int cg0  = (pos0 & 3) << 3;            // k-chunk (shorts)
    const int ldsb = wave * 1024;                // shorts; +512 for p=1

    f32x4 acc[4][4];
#pragma unroll
    for (int i = 0; i < 4; i++)
#pragma unroll
        for (int n = 0; n < 4; n++) acc[i][n] = (f32x4)0.f;

    for (int k0 = 0; k0 < K; k0 += 32) {
        __syncthreads();
        {
            const unsigned short* ga0 = A  + (size_t)(m0 + row0) * K + k0 + cg0;
            const unsigned short* ga1 = A  + (size_t)(m0 + row1) * K + k0 + cg0;
            const unsigned short* gb0 = Bt + (size_t)(n0 + row0) * K + k0 + cg0;
            const unsigned short* gb1 = Bt + (size_t)(n0 + row1) * K + k0 + cg0;
            __builtin_amdgcn_global_load_lds(AS_GLOBAL(ga0), AS_LDS(As + ldsb),       16, 0, 0);
            __builtin_amdgcn_global_load_lds(AS_GLOBAL(ga1), AS_LDS(As + ldsb + 512), 16, 0, 0);
            __builtin_amdgcn_global_load_lds(AS_GLOBAL(gb0), AS_LDS(Bs + ldsb),       16, 0, 0);
            __builtin_amdgcn_global_load_lds(AS_GLOBAL(gb1), AS_LDS(Bs + ldsb + 512), 16, 0, 0);
        }
        __syncthreads();
        bf16x8 af[4], bfr[4];
#pragma unroll
        for (int i = 0; i < 4; i++)
            af[i] = *(const bf16x8*)(As + (wm + i * 16 + lm) * 32 + q * 8);
#pragma unroll
        for (int n = 0; n < 4; n++)
            bfr[n] = *(const bf16x8*)(Bs + (wn + n * 16 + lm) * 32 + q * 8);
#pragma unroll
        for (int i = 0; i < 4; i++)
#pragma unroll
            for (int n = 0; n < 4; n++)
                acc[i][n] = __builtin_amdgcn_mfma_f32_16x16x32_bf16(af[i], bfr[n], acc[i][n], 0, 0, 0);
    }

    // epilogue: D row = q*4 + r, col = lm (within each 16x16 tile)
#pragma unroll
    for (int i = 0; i < 4; i++) {
#pragma unroll
        for (int n = 0; n < 4; n++) {
            int gc = n0 + wn + n * 16 + lm;
            float bv = bias[gc];
#pragma unroll
            for (int r = 0; r < 4; r++) {
                int gr = m0 + wm + i * 16 + q * 4 + r;
                float v = acc[i][n][r] + bv;
                if (MODE == 0) {
                    ((unsigned short*)outp)[(size_t)gr * N + gc] = f2b(v);
                } else if (MODE == 1) {
                    float g = 0.5f * v * (1.f + erff(v * 0.70710678118654752f));
                    ((unsigned short*)outp)[(size_t)gr * N + gc] = f2b(g);
                } else {
                    ((float*)outp)[(size_t)gr * N + gc] += v;
                }
            }
        }
    }
}

// ---------------- MFMA flash attention, adds into fp32 residual ----------------
// grid = 2048: blk = ((b*16 + h)*16 + qt); 64 q-rows per block, 4 waves x 16 rows.
__global__ __launch_bounds__(256) void attn_k(
    const unsigned short* __restrict__ qb,
    const unsigned short* __restrict__ kb,
    const unsigned short* __restrict__ vb,
    float* __restrict__ x)
{
    __shared__ unsigned short Qs[64 * 72];
    __shared__ unsigned short Ks[64 * 72];
    __shared__ unsigned short Vst[64 * 64];
    __shared__ unsigned short Ps[4][16 * 72];

    const int t    = threadIdx.x;
    const int blk  = blockIdx.x;
    const int qt   = blk & 15;
    const int h    = (blk >> 4) & 15;
    const int b    = blk >> 8;
    const int w    = t >> 6;
    const int lane = t & 63;
    const int l15  = lane & 15;
    const int quad = lane >> 4;

    // ---- stage Q tile (64 rows x 64 d) ----
    {
        int r  = t >> 2;
        int dc = (t & 3) << 4;
        const uint4* src = (const uint4*)(qb + ((size_t)(b * 1024 + qt * 64 + r)) * 1024 + h * 64 + dc);
        uint4 u0 = src[0], u1 = src[1];
        *(uint4*)(Qs + r * 72 + dc)     = u0;
        *(uint4*)(Qs + r * 72 + dc + 8) = u1;
    }
    __syncthreads();
    bf16x8 qf0 = *(const bf16x8*)(Qs + (w * 16 + l15) * 72 + quad * 8);
    bf16x8 qf1 = *(const bf16x8*)(Qs + (w * 16 + l15) * 72 + 32 + quad * 8);

    float m_r[4], l_r[4];
    f32x4 O[4];
#pragma unroll
    for (int r = 0; r < 4; r++) { m_r[r] = -1e30f; l_r[r] = 0.f; }
#pragma unroll
    for (int n = 0; n < 4; n++) O[n] = (f32x4)0.f;

    for (int kt = 0; kt < 16; ++kt) {
        __syncthreads();
        // ---- stage K tile [key][d] ----
        {
            int r  = t >> 2;
            int dc = (t & 3) << 4;
            const uint4* src = (const uint4*)(kb + ((size_t)(b * 1024 + kt * 64 + r)) * 1024 + h * 64 + dc);
            uint4 u0 = src[0], u1 = src[1];
            *(uint4*)(Ks + r * 72 + dc)     = u0;
            *(uint4*)(Ks + r * 72 + dc + 8) = u1;
        }
        // ---- stage V tile transposed+swizzled [d][key] ----
        {
            int r2  = t >> 3;            // key pair index 0..31
            int dc  = (t & 7) << 3;      // d chunk 0,8,..,56
            const unsigned short* v0 = vb + ((size_t)(b * 1024 + kt * 64 + 2 * r2)) * 1024 + h * 64 + dc;
            uint4 a0 = *(const uint4*)(v0);
            uint4 a1 = *(const uint4*)(v0 + 1024);
            const unsigned short* s0 = (const unsigned short*)&a0;
            const unsigned short* s1 = (const unsigned short*)&a1;
            int dc3 = dc >> 3;
            int lc  = r2 >> 2;           // logical 8-key chunk
            int ko  = (2 * r2) & 7;      // key offset within chunk
#pragma unroll
            for (int j = 0; j < 8; j++) {
                int sw = (j ^ dc3) & 7;
                unsigned int pk = (unsigned int)s0[j] | ((unsigned int)s1[j] << 16);
                *(unsigned int*)(Vst + (dc + j) * 64 + ((lc ^ sw) << 3) + ko) = pk;
            }
        }
        __syncthreads();

        // ---- S = Q K^T (16 q-rows x 64 keys per wave) ----
        f32x4 s[4];
#pragma unroll
        for (int nt = 0; nt < 4; nt++) {
            bf16x8 k0 = *(const bf16x8*)(Ks + (nt * 16 + l15) * 72 + quad * 8);
            bf16x8 k1 = *(const bf16x8*)(Ks + (nt * 16 + l15) * 72 + 32 + quad * 8);
            f32x4 acc = (f32x4)0.f;
            acc = __builtin_amdgcn_mfma_f32_16x16x32_bf16(qf0, k0, acc, 0, 0, 0);
            acc = __builtin_amdgcn_mfma_f32_16x16x32_bf16(qf1, k1, acc, 0, 0, 0);
            s[nt] = acc * 0.03125f;   // SCALE = 1024^-0.5
        }

        // ---- online softmax (rows = quad*4+r; reduce cols via xor-shuffles) ----
#pragma unroll
        for (int r = 0; r < 4; r++) {
            float tm = fmaxf(fmaxf(s[0][r], s[1][r]), fmaxf(s[2][r], s[3][r]));
            tm = fmaxf(tm, __shfl_xor(tm, 1));
            tm = fmaxf(tm, __shfl_xor(tm, 2));
            tm = fmaxf(tm, __shfl_xor(tm, 4));
            tm = fmaxf(tm, __shfl_xor(tm, 8));
            float nm    = fmaxf(m_r[r], tm);
            float alpha = __expf(m_r[r] - nm);
            float ls = 0.f;
#pragma unroll
            for (int nt = 0; nt < 4; nt++) {
                float p = __expf(s[nt][r] - nm);
                s[nt][r] = p;
                ls += p;
            }
            ls += __shfl_xor(ls, 1);
            ls += __shfl_xor(ls, 2);
            ls += __shfl_xor(ls, 4);
            ls += __shfl_xor(ls, 8);
            l_r[r] = l_r[r] * alpha + ls;
            m_r[r] = nm;
            O[0][r] *= alpha; O[1][r] *= alpha; O[2][r] *= alpha; O[3][r] *= alpha;
        }

        // ---- P: C-layout -> A-layout via per-wave LDS round-trip ----
        unsigned short* pw = Ps[w];
#pragma unroll
        for (int nt = 0; nt < 4; nt++)
#pragma unroll
            for (int r = 0; r < 4; r++)
                pw[(quad * 4 + r) * 72 + nt * 16 + l15] = f2b(s[nt][r]);
        bf16x8 pf0 = *(const bf16x8*)(pw + l15 * 72 + quad * 8);
        bf16x8 pf1 = *(const bf16x8*)(pw + l15 * 72 + 32 + quad * 8);

        // ---- O += P V ----
#pragma unroll
        for (int nt = 0; nt < 4; nt++) {
            int d  = nt * 16 + l15;
            int sw = (d ^ (d >> 3)) & 7;
            bf16x8 vf0 = *(const bf16x8*)(Vst + d * 64 + ((quad ^ sw) << 3));
            bf16x8 vf1 = *(const bf16x8*)(Vst + d * 64 + (((4 + quad) ^ sw) << 3));
            O[nt] = __builtin_amdgcn_mfma_f32_16x16x32_bf16(pf0, vf0, O[nt], 0, 0, 0);
            O[nt] = __builtin_amdgcn_mfma_f32_16x16x32_bf16(pf1, vf1, O[nt], 0, 0, 0);
        }
    }

    // ---- epilogue: x += O / l  (C-layout: row = quad*4+r, col = nt*16+l15) ----
    float inv[4];
#pragma unroll
    for (int r = 0; r < 4; r++) inv[r] = 1.f / l_r[r];
#pragma unroll
    for (int nt = 0; nt < 4; nt++) {
#pragma unroll
        for (int r = 0; r < 4; r++) {
            size_t idx = ((size_t)(b * 1024 + qt * 64 + w * 16 + quad * 4 + r)) * 1024
                       + h * 64 + nt * 16 + l15;
            x[idx] += O[nt][r] * inv[r];
        }
    }
}

// ---------------- launch ----------------
extern "C" void kernel_launch(void* const* d_in, const int* in_sizes, int n_in,
                              void* d_out, int out_size, void* d_ws, size_t ws_size,
                              hipStream_t stream)
{
    (void)in_sizes; (void)n_in; (void)out_size; (void)ws_size;
    const float* x_in  = (const float*)d_in[0];
    const float* Wq    = (const float*)d_in[1];
    const float* bq    = (const float*)d_in[2];
    const float* Wk    = (const float*)d_in[3];
    const float* bk    = (const float*)d_in[4];
    const float* Wv    = (const float*)d_in[5];
    const float* bv    = (const float*)d_in[6];
    const float* W1    = (const float*)d_in[7];
    const float* b1    = (const float*)d_in[8];
    const float* W2    = (const float*)d_in[9];
    const float* b2    = (const float*)d_in[10];
    const float* gamma = (const float*)d_in[11];
    const float* beta  = (const float*)d_in[12];

    char* base = (char*)d_ws;
    float*          xf   = (float*)(base);                               // 32 MB
    unsigned short* xn   = (unsigned short*)(base + 33554432);           // 16 MB
    // union region: q/k/v (48 MB) overlaps h1 (64 MB) — disjoint lifetimes
    unsigned short* qbuf = (unsigned short*)(base + 50331648);
    unsigned short* kbuf = (unsigned short*)(base + 50331648 + 16777216);
    unsigned short* vbuf = (unsigned short*)(base + 50331648 + 33554432);
    unsigned short* h1   = (unsigned short*)(base + 50331648);           // 64 MB
    char* wbase = base + 50331648 + 67108864;
    unsigned short* WqT = (unsigned short*)(wbase);                      // 2 MB
    unsigned short* WkT = (unsigned short*)(wbase + 2097152);
    unsigned short* WvT = (unsigned short*)(wbase + 4194304);
    unsigned short* W1T = (unsigned short*)(wbase + 6291456);            // 8 MB
    unsigned short* W2T = (unsigned short*)(wbase + 14680064);           // 8 MB

    // once per launch: weight transposes (f32 -> bf16 [N][K]) + residual copy
    transpose_f32_to_bf16<<<dim3(32, 32),  256, 0, stream>>>(Wq, WqT, 1024, 1024);
    transpose_f32_to_bf16<<<dim3(32, 32),  256, 0, stream>>>(Wk, WkT, 1024, 1024);
    transpose_f32_to_bf16<<<dim3(32, 32),  256, 0, stream>>>(Wv, WvT, 1024, 1024);
    transpose_f32_to_bf16<<<dim3(128, 32), 256, 0, stream>>>(W1, W1T, 1024, 4096);
    transpose_f32_to_bf16<<<dim3(32, 128), 256, 0, stream>>>(W2, W2T, 4096, 1024);
    copy_f32<<<4096, 256, 0, stream>>>(x_in, xf);

    for (int layer = 0; layer < 6; ++layer) {
        layernorm_k<<<8192, 256, 0, stream>>>(xf, gamma, beta, xn);
        gemm_bt<0><<<dim3(8, 64),  256, 0, stream>>>(xn, WqT, bq, qbuf, 8192, 1024, 1024);
        gemm_bt<0><<<dim3(8, 64),  256, 0, stream>>>(xn, WkT, bk, kbuf, 8192, 1024, 1024);
        gemm_bt<0><<<dim3(8, 64),  256, 0, stream>>>(xn, WvT, bv, vbuf, 8192, 1024, 1024);
        attn_k<<<2048, 256, 0, stream>>>(qbuf, kbuf, vbuf, xf);
        layernorm_k<<<8192, 256, 0, stream>>>(xf, gamma, beta, xn);
        gemm_bt<1><<<dim3(32, 64), 256, 0, stream>>>(xn, W1T, b1, h1, 8192, 4096, 1024);
        gemm_bt<2><<<dim3(8, 64),  256, 0, stream>>>(h1, W2T, b2, xf, 8192, 1024, 4096);
    }
    copy_f32<<<4096, 256, 0, stream>>>(xf, (float*)d_out);
}

// Round 6
// 2929.421 us; speedup vs baseline: 3.3555x; 1.0026x over previous
//
#include <hip/hip_runtime.h>
#include <cstdint>
#include <cmath>

typedef short bf16x8 __attribute__((ext_vector_type(8)));
typedef float f32x4 __attribute__((ext_vector_type(4)));

#define AS_GLOBAL(p) (const __attribute__((address_space(1))) void*)(p)
#define AS_LDS(p)    (__attribute__((address_space(3))) void*)(p)

// SCALE * log2(e) folded into Q epilogue: 2^-5 * 1.44269504
#define QSCALE 0.04508422002778f

__device__ inline unsigned short f2b(float f) {
    // round-half-up bf16: 1 ulp vs RTNE on ties only
    return (unsigned short)((__float_as_uint(f) + 0x8000u) >> 16);
}

// ---------------- weight transpose+cast: W[K][N] (f32) -> Wt[N][K] (bf16) ----------------
__global__ __launch_bounds__(256) void transpose_f32_to_bf16(
    const float* __restrict__ W, unsigned short* __restrict__ Wt, int K, int N)
{
    __shared__ unsigned short sh[32][33];
    int n0 = blockIdx.x * 32;
    int k0 = blockIdx.y * 32;
    int tr = threadIdx.x >> 5;   // 0..7
    int tc = threadIdx.x & 31;   // 0..31
#pragma unroll
    for (int i = 0; i < 4; i++)
        sh[tr + i * 8][tc] = f2b(W[(size_t)(k0 + tr + i * 8) * N + n0 + tc]);
    __syncthreads();
#pragma unroll
    for (int i = 0; i < 4; i++)
        Wt[(size_t)(n0 + tr + i * 8) * K + k0 + tc] = sh[tc][tr + i * 8];
}

// ---------------- fp32 copy (8 elems/thread) ----------------
__global__ __launch_bounds__(256) void copy_f32(const float* __restrict__ in,
                                                float* __restrict__ out)
{
    size_t i = ((size_t)blockIdx.x * 256 + threadIdx.x) * 8;
    f32x4 a = *(const f32x4*)(in + i);
    f32x4 b = *(const f32x4*)(in + i + 4);
    *(f32x4*)(out + i) = a;
    *(f32x4*)(out + i + 4) = b;
}

// ---------------- layernorm: fp32 in -> bf16 out ----------------
__global__ __launch_bounds__(256) void layernorm_k(
    const float* __restrict__ x, const float* __restrict__ gamma,
    const float* __restrict__ beta, unsigned short* __restrict__ out)
{
    int row = blockIdx.x;
    int t = threadIdx.x;
    f32x4 v = *(const f32x4*)(x + (size_t)row * 1024 + t * 4);
    float s  = v[0] + v[1] + v[2] + v[3];
    float s2 = v[0]*v[0] + v[1]*v[1] + v[2]*v[2] + v[3]*v[3];
#pragma unroll
    for (int off = 32; off >= 1; off >>= 1) {
        s  += __shfl_xor(s,  off);
        s2 += __shfl_xor(s2, off);
    }
    __shared__ float red[8];
    int w = t >> 6;
    if ((t & 63) == 0) { red[w] = s; red[4 + w] = s2; }
    __syncthreads();
    s  = red[0] + red[1] + red[2] + red[3];
    s2 = red[4] + red[5] + red[6] + red[7];
    float mu  = s * (1.f / 1024.f);
    float var = s2 * (1.f / 1024.f) - mu * mu;
    float rs  = rsqrtf(var + 1e-5f);
    int c = t * 4;
    f32x4 g = *(const f32x4*)(gamma + c);
    f32x4 be = *(const f32x4*)(beta + c);
    unsigned int lo, hi;
    {
        float o0 = (v[0] - mu) * rs * g[0] + be[0];
        float o1 = (v[1] - mu) * rs * g[1] + be[1];
        float o2 = (v[2] - mu) * rs * g[2] + be[2];
        float o3 = (v[3] - mu) * rs * g[3] + be[3];
        lo = (unsigned)f2b(o0) | ((unsigned)f2b(o1) << 16);
        hi = (unsigned)f2b(o2) | ((unsigned)f2b(o3) << 16);
    }
    uint2 pk; pk.x = lo; pk.y = hi;
    *(uint2*)(out + (size_t)row * 1024 + c) = pk;
}

// ---------------- MFMA GEMM: C[M][N] = A[M][K](bf16) * Bt[N][K]^T(bf16) + bias(f32) ----------------
// m97-style staging: global_load_lds width=16 into unpadded [row][k] pitch-32-short tiles.
// MODE 0: bf16 out = v + bias[col]
// MODE 1: bf16 out = gelu_exact(v + bias[col])
// MODE 2: f32 out += v + bias[col]     (residual add)
// MODE 3: bf16 out = v + bias[row]     (V^T GEMM: bias indexed by output row=dim)
// MODE 4: bf16 out = (v + bias[col]) * QSCALE   (Q GEMM, softmax pre-scale)
template<int MODE>
__global__ __launch_bounds__(256) void gemm_bt(
    const unsigned short* __restrict__ A,
    const unsigned short* __restrict__ Bt,
    const float* __restrict__ bias,
    void* __restrict__ outp,
    int M, int N, int K)
{
    __shared__ unsigned short As[128 * 32];
    __shared__ unsigned short Bs[128 * 32];
    const int t = threadIdx.x;
    const int n0 = blockIdx.x * 128;
    const int m0 = blockIdx.y * 128;
    const int lane = t & 63;
    const int wave = t >> 6;
    const int wm = (wave >> 1) * 64;
    const int wn = (wave & 1) * 64;
    const int lm = lane & 15;
    const int q  = lane >> 4;

    const int pos0 = wave * 128 + lane;
    const int row0 = pos0 >> 2;
    const int row1 = (pos0 + 64) >> 2;
    const int cg0  = (pos0 & 3) << 3;
    const int ldsb = wave * 1024;

    f32x4 acc[4][4];
#pragma unroll
    for (int i = 0; i < 4; i++)
#pragma unroll
        for (int n = 0; n < 4; n++) acc[i][n] = (f32x4)0.f;

    for (int k0 = 0; k0 < K; k0 += 32) {
        __syncthreads();
        {
            const unsigned short* ga0 = A  + (size_t)(m0 + row0) * K + k0 + cg0;
            const unsigned short* ga1 = A  + (size_t)(m0 + row1) * K + k0 + cg0;
            const unsigned short* gb0 = Bt + (size_t)(n0 + row0) * K + k0 + cg0;
            const unsigned short* gb1 = Bt + (size_t)(n0 + row1) * K + k0 + cg0;
            __builtin_amdgcn_global_load_lds(AS_GLOBAL(ga0), AS_LDS(As + ldsb),       16, 0, 0);
            __builtin_amdgcn_global_load_lds(AS_GLOBAL(ga1), AS_LDS(As + ldsb + 512), 16, 0, 0);
            __builtin_amdgcn_global_load_lds(AS_GLOBAL(gb0), AS_LDS(Bs + ldsb),       16, 0, 0);
            __builtin_amdgcn_global_load_lds(AS_GLOBAL(gb1), AS_LDS(Bs + ldsb + 512), 16, 0, 0);
        }
        __syncthreads();
        bf16x8 af[4], bfr[4];
#pragma unroll
        for (int i = 0; i < 4; i++)
            af[i] = *(const bf16x8*)(As + (wm + i * 16 + lm) * 32 + q * 8);
#pragma unroll
        for (int n = 0; n < 4; n++)
            bfr[n] = *(const bf16x8*)(Bs + (wn + n * 16 + lm) * 32 + q * 8);
#pragma unroll
        for (int i = 0; i < 4; i++)
#pragma unroll
            for (int n = 0; n < 4; n++)
                acc[i][n] = __builtin_amdgcn_mfma_f32_16x16x32_bf16(af[i], bfr[n], acc[i][n], 0, 0, 0);
    }

    // epilogue: D row = q*4 + r, col = lm (within each 16x16 tile)
#pragma unroll
    for (int i = 0; i < 4; i++) {
#pragma unroll
        for (int n = 0; n < 4; n++) {
            int gc = n0 + wn + n * 16 + lm;
            float bv = (MODE == 3) ? 0.f : bias[gc];
#pragma unroll
            for (int r = 0; r < 4; r++) {
                int gr = m0 + wm + i * 16 + q * 4 + r;
                float v = acc[i][n][r] + ((MODE == 3) ? bias[gr] : bv);
                if (MODE == 0) {
                    ((unsigned short*)outp)[(size_t)gr * N + gc] = f2b(v);
                } else if (MODE == 1) {
                    float g = 0.5f * v * (1.f + erff(v * 0.70710678118654752f));
                    ((unsigned short*)outp)[(size_t)gr * N + gc] = f2b(g);
                } else if (MODE == 2) {
                    ((float*)outp)[(size_t)gr * N + gc] += v;
                } else if (MODE == 3) {
                    ((unsigned short*)outp)[(size_t)gr * N + gc] = f2b(v);
                } else {
                    ((unsigned short*)outp)[(size_t)gr * N + gc] = f2b(v * QSCALE);
                }
            }
        }
    }
}

// ---------------- MFMA flash attention, adds into fp32 residual ----------------
// grid = 2048: blk = ((b*16 + h)*16 + qt); 64 q-rows per block, 4 waves x 16 rows.
// Q arrives pre-scaled by SCALE*log2(e); softmax in exp2 domain.
// vtb is V^T [1024 dims][8192 tokens] -> staging is coalesced row loads, no transpose.
__global__ __launch_bounds__(256) void attn_k(
    const unsigned short* __restrict__ qb,
    const unsigned short* __restrict__ kb,
    const unsigned short* __restrict__ vtb,
    float* __restrict__ x)
{
    __shared__ unsigned short Qs[64 * 72];
    __shared__ unsigned short Ks[64 * 72];
    __shared__ unsigned short Vst[64 * 72];
    __shared__ unsigned short Ps[4][16 * 72];

    const int t    = threadIdx.x;
    const int blk  = blockIdx.x;
    const int qt   = blk & 15;
    const int h    = (blk >> 4) & 15;
    const int b    = blk >> 8;
    const int w    = t >> 6;
    const int lane = t & 63;
    const int l15  = lane & 15;
    const int quad = lane >> 4;

    // ---- stage Q tile (64 rows x 64 d) ----
    {
        int r  = t >> 2;
        int dc = (t & 3) << 4;
        const uint4* src = (const uint4*)(qb + ((size_t)(b * 1024 + qt * 64 + r)) * 1024 + h * 64 + dc);
        uint4 u0 = src[0], u1 = src[1];
        *(uint4*)(Qs + r * 72 + dc)     = u0;
        *(uint4*)(Qs + r * 72 + dc + 8) = u1;
    }
    __syncthreads();
    bf16x8 qf0 = *(const bf16x8*)(Qs + (w * 16 + l15) * 72 + quad * 8);
    bf16x8 qf1 = *(const bf16x8*)(Qs + (w * 16 + l15) * 72 + 32 + quad * 8);

    float m_r[4], l_r[4];
    f32x4 O[4];
#pragma unroll
    for (int r = 0; r < 4; r++) { m_r[r] = -1e30f; l_r[r] = 0.f; }
#pragma unroll
    for (int n = 0; n < 4; n++) O[n] = (f32x4)0.f;

    for (int kt = 0; kt < 16; ++kt) {
        __syncthreads();
        // ---- stage K tile [key][d] ----
        {
            int r  = t >> 2;
            int dc = (t & 3) << 4;
            const uint4* src = (const uint4*)(kb + ((size_t)(b * 1024 + kt * 64 + r)) * 1024 + h * 64 + dc);
            uint4 u0 = src[0], u1 = src[1];
            *(uint4*)(Ks + r * 72 + dc)     = u0;
            *(uint4*)(Ks + r * 72 + dc + 8) = u1;
        }
        // ---- stage V^T tile [d][key] (already transposed in global) ----
        {
            int d  = t >> 2;             // 0..63
            int kc = (t & 3) << 4;       // key chunk 0,16,32,48
            const uint4* src = (const uint4*)(vtb + (size_t)(h * 64 + d) * 8192 + b * 1024 + kt * 64 + kc);
            uint4 u0 = src[0], u1 = src[1];
            *(uint4*)(Vst + d * 72 + kc)     = u0;
            *(uint4*)(Vst + d * 72 + kc + 8) = u1;
        }
        __syncthreads();

        // ---- S = Q K^T (16 q-rows x 64 keys per wave); already in log2 units ----
        f32x4 s[4];
#pragma unroll
        for (int nt = 0; nt < 4; nt++) {
            bf16x8 k0 = *(const bf16x8*)(Ks + (nt * 16 + l15) * 72 + quad * 8);
            bf16x8 k1 = *(const bf16x8*)(Ks + (nt * 16 + l15) * 72 + 32 + quad * 8);
            f32x4 acc = (f32x4)0.f;
            acc = __builtin_amdgcn_mfma_f32_16x16x32_bf16(qf0, k0, acc, 0, 0, 0);
            acc = __builtin_amdgcn_mfma_f32_16x16x32_bf16(qf1, k1, acc, 0, 0, 0);
            s[nt] = acc;
        }

        // ---- online softmax, exp2 domain (rows = quad*4+r) ----
#pragma unroll
        for (int r = 0; r < 4; r++) {
            float tm = fmaxf(fmaxf(s[0][r], s[1][r]), fmaxf(s[2][r], s[3][r]));
            tm = fmaxf(tm, __shfl_xor(tm, 1));
            tm = fmaxf(tm, __shfl_xor(tm, 2));
            tm = fmaxf(tm, __shfl_xor(tm, 4));
            tm = fmaxf(tm, __shfl_xor(tm, 8));
            float nm    = fmaxf(m_r[r], tm);
            float alpha = exp2f(m_r[r] - nm);
            float ls = 0.f;
#pragma unroll
            for (int nt = 0; nt < 4; nt++) {
                float p = exp2f(s[nt][r] - nm);
                s[nt][r] = p;
                ls += p;
            }
            ls += __shfl_xor(ls, 1);
            ls += __shfl_xor(ls, 2);
            ls += __shfl_xor(ls, 4);
            ls += __shfl_xor(ls, 8);
            l_r[r] = l_r[r] * alpha + ls;
            m_r[r] = nm;
            O[0][r] *= alpha; O[1][r] *= alpha; O[2][r] *= alpha; O[3][r] *= alpha;
        }

        // ---- P: C-layout -> A-layout via per-wave LDS round-trip (trunc-round) ----
        unsigned short* pw = Ps[w];
#pragma unroll
        for (int nt = 0; nt < 4; nt++)
#pragma unroll
            for (int r = 0; r < 4; r++)
                pw[(quad * 4 + r) * 72 + nt * 16 + l15] = f2b(s[nt][r]);
        bf16x8 pf0 = *(const bf16x8*)(pw + l15 * 72 + quad * 8);
        bf16x8 pf1 = *(const bf16x8*)(pw + l15 * 72 + 32 + quad * 8);

        // ---- O += P V  (B-frag: lane n = d = nt*16+l15, k = key contiguous) ----
#pragma unroll
        for (int nt = 0; nt < 4; nt++) {
            int d = nt * 16 + l15;
            bf16x8 vf0 = *(const bf16x8*)(Vst + d * 72 + quad * 8);
            bf16x8 vf1 = *(const bf16x8*)(Vst + d * 72 + 32 + quad * 8);
            O[nt] = __builtin_amdgcn_mfma_f32_16x16x32_bf16(pf0, vf0, O[nt], 0, 0, 0);
            O[nt] = __builtin_amdgcn_mfma_f32_16x16x32_bf16(pf1, vf1, O[nt], 0, 0, 0);
        }
    }

    // ---- epilogue: x += O / l  (C-layout: row = quad*4+r, col = nt*16+l15) ----
    float inv[4];
#pragma unroll
    for (int r = 0; r < 4; r++) inv[r] = 1.f / l_r[r];
#pragma unroll
    for (int nt = 0; nt < 4; nt++) {
#pragma unroll
        for (int r = 0; r < 4; r++) {
            size_t idx = ((size_t)(b * 1024 + qt * 64 + w * 16 + quad * 4 + r)) * 1024
                       + h * 64 + nt * 16 + l15;
            x[idx] += O[nt][r] * inv[r];
        }
    }
}

// ---------------- launch ----------------
extern "C" void kernel_launch(void* const* d_in, const int* in_sizes, int n_in,
                              void* d_out, int out_size, void* d_ws, size_t ws_size,
                              hipStream_t stream)
{
    (void)in_sizes; (void)n_in; (void)out_size; (void)ws_size;
    const float* x_in  = (const float*)d_in[0];
    const float* Wq    = (const float*)d_in[1];
    const float* bq    = (const float*)d_in[2];
    const float* Wk    = (const float*)d_in[3];
    const float* bk    = (const float*)d_in[4];
    const float* Wv    = (const float*)d_in[5];
    const float* bv    = (const float*)d_in[6];
    const float* W1    = (const float*)d_in[7];
    const float* b1    = (const float*)d_in[8];
    const float* W2    = (const float*)d_in[9];
    const float* b2    = (const float*)d_in[10];
    const float* gamma = (const float*)d_in[11];
    const float* beta  = (const float*)d_in[12];

    char* base = (char*)d_ws;
    float*          xf   = (float*)(base);                               // 32 MB
    unsigned short* xn   = (unsigned short*)(base + 33554432);           // 16 MB
    // union region: q/k/vt (48 MB) overlaps h1 (64 MB) — disjoint lifetimes
    unsigned short* qbuf = (unsigned short*)(base + 50331648);
    unsigned short* kbuf = (unsigned short*)(base + 50331648 + 16777216);
    unsigned short* vtb  = (unsigned short*)(base + 50331648 + 33554432); // V^T [1024][8192]
    unsigned short* h1   = (unsigned short*)(base + 50331648);           // 64 MB
    char* wbase = base + 50331648 + 67108864;
    unsigned short* WqT = (unsigned short*)(wbase);                      // 2 MB
    unsigned short* WkT = (unsigned short*)(wbase + 2097152);
    unsigned short* WvT = (unsigned short*)(wbase + 4194304);
    unsigned short* W1T = (unsigned short*)(wbase + 6291456);            // 8 MB
    unsigned short* W2T = (unsigned short*)(wbase + 14680064);           // 8 MB

    // once per launch: weight transposes (f32 -> bf16 [N][K]) + residual copy
    transpose_f32_to_bf16<<<dim3(32, 32),  256, 0, stream>>>(Wq, WqT, 1024, 1024);
    transpose_f32_to_bf16<<<dim3(32, 32),  256, 0, stream>>>(Wk, WkT, 1024, 1024);
    transpose_f32_to_bf16<<<dim3(32, 32),  256, 0, stream>>>(Wv, WvT, 1024, 1024);
    transpose_f32_to_bf16<<<dim3(128, 32), 256, 0, stream>>>(W1, W1T, 1024, 4096);
    transpose_f32_to_bf16<<<dim3(32, 128), 256, 0, stream>>>(W2, W2T, 4096, 1024);
    copy_f32<<<4096, 256, 0, stream>>>(x_in, xf);

    for (int layer = 0; layer < 6; ++layer) {
        layernorm_k<<<8192, 256, 0, stream>>>(xf, gamma, beta, xn);
        gemm_bt<4><<<dim3(8, 64),  256, 0, stream>>>(xn, WqT, bq, qbuf, 8192, 1024, 1024);
        gemm_bt<0><<<dim3(8, 64),  256, 0, stream>>>(xn, WkT, bk, kbuf, 8192, 1024, 1024);
        // V^T = WvT(rows=dim) x xn(rows=token): out [1024][8192], bias by row
        gemm_bt<3><<<dim3(64, 8),  256, 0, stream>>>(WvT, xn, bv, vtb, 1024, 8192, 1024);
        attn_k<<<2048, 256, 0, stream>>>(qbuf, kbuf, vtb, xf);
        layernorm_k<<<8192, 256, 0, stream>>>(xf, gamma, beta, xn);
        gemm_bt<1><<<dim3(32, 64), 256, 0, stream>>>(xn, W1T, b1, h1, 8192, 4096, 1024);
        gemm_bt<2><<<dim3(8, 64),  256, 0, stream>>>(h1, W2T, b2, xf, 8192, 1024, 4096);
    }
    copy_f32<<<4096, 256, 0, stream>>>(xf, (float*)d_out);
}

// Round 7
// 2771.116 us; speedup vs baseline: 3.5472x; 1.0571x over previous
//
#include <hip/hip_runtime.h>
#include <cstdint>
#include <cmath>

typedef short bf16x8 __attribute__((ext_vector_type(8)));
typedef float f32x4 __attribute__((ext_vector_type(4)));

#define AS_GLOBAL(p) (const __attribute__((address_space(1))) void*)(p)
#define AS_LDS(p)    (__attribute__((address_space(3))) void*)(p)

// SCALE * log2(e) folded into Q epilogue: 2^-5 * 1.44269504
#define QSCALE 0.04508422002778f

__device__ inline float b2f(unsigned short u) {
    union { unsigned int i; float f; } c; c.i = ((unsigned int)u) << 16; return c.f;
}
__device__ inline unsigned short f2b(float f) {
    return (unsigned short)((__float_as_uint(f) + 0x8000u) >> 16);
}
// pack 4 floats -> 4 bf16 (round-half-up) in a uint2
__device__ inline uint2 pk4(float a, float b, float c, float d) {
    unsigned ua = __float_as_uint(a) + 0x8000u;
    unsigned ub = __float_as_uint(b) + 0x8000u;
    unsigned uc = __float_as_uint(c) + 0x8000u;
    unsigned ud = __float_as_uint(d) + 0x8000u;
    uint2 r;
    r.x = (ua >> 16) | (ub & 0xffff0000u);
    r.y = (uc >> 16) | (ud & 0xffff0000u);
    return r;
}

// ---------------- weight transpose+cast: W[K][N] (f32) -> Wt[N][K] (bf16) ----------------
__global__ __launch_bounds__(256) void transpose_f32_to_bf16(
    const float* __restrict__ W, unsigned short* __restrict__ Wt, int K, int N)
{
    __shared__ unsigned short sh[32][33];
    int n0 = blockIdx.x * 32;
    int k0 = blockIdx.y * 32;
    int tr = threadIdx.x >> 5;
    int tc = threadIdx.x & 31;
#pragma unroll
    for (int i = 0; i < 4; i++)
        sh[tr + i * 8][tc] = f2b(W[(size_t)(k0 + tr + i * 8) * N + n0 + tc]);
    __syncthreads();
#pragma unroll
    for (int i = 0; i < 4; i++)
        Wt[(size_t)(n0 + tr + i * 8) * K + k0 + tc] = sh[tc][tr + i * 8];
}

// ---------------- fp32 copy (8 elems/thread) ----------------
__global__ __launch_bounds__(256) void copy_f32(const float* __restrict__ in,
                                                float* __restrict__ out)
{
    size_t i = ((size_t)blockIdx.x * 256 + threadIdx.x) * 8;
    f32x4 a = *(const f32x4*)(in + i);
    f32x4 b = *(const f32x4*)(in + i + 4);
    *(f32x4*)(out + i) = a;
    *(f32x4*)(out + i + 4) = b;
}

// ---------------- layernorm: fp32 in -> bf16 out ----------------
__global__ __launch_bounds__(256) void layernorm_k(
    const float* __restrict__ x, const float* __restrict__ gamma,
    const float* __restrict__ beta, unsigned short* __restrict__ out)
{
    int row = blockIdx.x;
    int t = threadIdx.x;
    f32x4 v = *(const f32x4*)(x + (size_t)row * 1024 + t * 4);
    float s  = v[0] + v[1] + v[2] + v[3];
    float s2 = v[0]*v[0] + v[1]*v[1] + v[2]*v[2] + v[3]*v[3];
#pragma unroll
    for (int off = 32; off >= 1; off >>= 1) {
        s  += __shfl_xor(s,  off);
        s2 += __shfl_xor(s2, off);
    }
    __shared__ float red[8];
    int w = t >> 6;
    if ((t & 63) == 0) { red[w] = s; red[4 + w] = s2; }
    __syncthreads();
    s  = red[0] + red[1] + red[2] + red[3];
    s2 = red[4] + red[5] + red[6] + red[7];
    float mu  = s * (1.f / 1024.f);
    float var = s2 * (1.f / 1024.f) - mu * mu;
    float rs  = rsqrtf(var + 1e-5f);
    int c = t * 4;
    f32x4 g = *(const f32x4*)(gamma + c);
    f32x4 be = *(const f32x4*)(beta + c);
    unsigned int lo, hi;
    {
        float o0 = (v[0] - mu) * rs * g[0] + be[0];
        float o1 = (v[1] - mu) * rs * g[1] + be[1];
        float o2 = (v[2] - mu) * rs * g[2] + be[2];
        float o3 = (v[3] - mu) * rs * g[3] + be[3];
        lo = (unsigned)f2b(o0) | ((unsigned)f2b(o1) << 16);
        hi = (unsigned)f2b(o2) | ((unsigned)f2b(o3) << 16);
    }
    uint2 pk; pk.x = lo; pk.y = hi;
    *(uint2*)(out + (size_t)row * 1024 + c) = pk;
}

// ---------------- MFMA GEMM: C[M][N] = A[M][K](bf16) * Bt[N][K]^T(bf16) + bias(f32) ----------------
// MODE 0: bf16 out = v + bias[col]
// MODE 1: bf16 out = gelu_exact(v + bias[col])
// MODE 2: f32 out += v + bias[col]     (residual add)
// MODE 3: bf16 out = v + bias[row]     (V^T GEMM: bias indexed by output row=dim)
// MODE 4: bf16 out = (v + bias[col]) * QSCALE   (Q GEMM, softmax pre-scale)
template<int MODE>
__global__ __launch_bounds__(256) void gemm_bt(
    const unsigned short* __restrict__ A,
    const unsigned short* __restrict__ Bt,
    const float* __restrict__ bias,
    void* __restrict__ outp,
    int M, int N, int K)
{
    __shared__ unsigned short As[128 * 32];
    __shared__ unsigned short Bs[128 * 32];
    const int t = threadIdx.x;
    const int n0 = blockIdx.x * 128;
    const int m0 = blockIdx.y * 128;
    const int lane = t & 63;
    const int wave = t >> 6;
    const int wm = (wave >> 1) * 64;
    const int wn = (wave & 1) * 64;
    const int lm = lane & 15;
    const int q  = lane >> 4;

    const int pos0 = wave * 128 + lane;
    const int row0 = pos0 >> 2;
    const int row1 = (pos0 + 64) >> 2;
    const int cg0  = (pos0 & 3) << 3;
    const int ldsb = wave * 1024;

    f32x4 acc[4][4];
#pragma unroll
    for (int i = 0; i < 4; i++)
#pragma unroll
        for (int n = 0; n < 4; n++) acc[i][n] = (f32x4)0.f;

    for (int k0 = 0; k0 < K; k0 += 32) {
        __syncthreads();
        {
            const unsigned short* ga0 = A  + (size_t)(m0 + row0) * K + k0 + cg0;
            const unsigned short* ga1 = A  + (size_t)(m0 + row1) * K + k0 + cg0;
            const unsigned short* gb0 = Bt + (size_t)(n0 + row0) * K + k0 + cg0;
            const unsigned short* gb1 = Bt + (size_t)(n0 + row1) * K + k0 + cg0;
            __builtin_amdgcn_global_load_lds(AS_GLOBAL(ga0), AS_LDS(As + ldsb),       16, 0, 0);
            __builtin_amdgcn_global_load_lds(AS_GLOBAL(ga1), AS_LDS(As + ldsb + 512), 16, 0, 0);
            __builtin_amdgcn_global_load_lds(AS_GLOBAL(gb0), AS_LDS(Bs + ldsb),       16, 0, 0);
            __builtin_amdgcn_global_load_lds(AS_GLOBAL(gb1), AS_LDS(Bs + ldsb + 512), 16, 0, 0);
        }
        __syncthreads();
        bf16x8 af[4], bfr[4];
#pragma unroll
        for (int i = 0; i < 4; i++)
            af[i] = *(const bf16x8*)(As + (wm + i * 16 + lm) * 32 + q * 8);
#pragma unroll
        for (int n = 0; n < 4; n++)
            bfr[n] = *(const bf16x8*)(Bs + (wn + n * 16 + lm) * 32 + q * 8);
#pragma unroll
        for (int i = 0; i < 4; i++)
#pragma unroll
            for (int n = 0; n < 4; n++)
                acc[i][n] = __builtin_amdgcn_mfma_f32_16x16x32_bf16(af[i], bfr[n], acc[i][n], 0, 0, 0);
    }

#pragma unroll
    for (int i = 0; i < 4; i++) {
#pragma unroll
        for (int n = 0; n < 4; n++) {
            int gc = n0 + wn + n * 16 + lm;
            float bv = (MODE == 3) ? 0.f : bias[gc];
#pragma unroll
            for (int r = 0; r < 4; r++) {
                int gr = m0 + wm + i * 16 + q * 4 + r;
                float v = acc[i][n][r] + ((MODE == 3) ? bias[gr] : bv);
                if (MODE == 0) {
                    ((unsigned short*)outp)[(size_t)gr * N + gc] = f2b(v);
                } else if (MODE == 1) {
                    float g = 0.5f * v * (1.f + erff(v * 0.70710678118654752f));
                    ((unsigned short*)outp)[(size_t)gr * N + gc] = f2b(g);
                } else if (MODE == 2) {
                    ((float*)outp)[(size_t)gr * N + gc] += v;
                } else if (MODE == 3) {
                    ((unsigned short*)outp)[(size_t)gr * N + gc] = f2b(v);
                } else {
                    ((unsigned short*)outp)[(size_t)gr * N + gc] = f2b(v * QSCALE);
                }
            }
        }
    }
}

// ---------------- MFMA flash attention v3: 128 q-rows/block, S^T orientation ----------------
// grid = 1024: blk = ((b*16 + h)*8 + qt); 4 waves x 32 q-rows.
// S^T = K·Q^T  (C col = l15 = qrow -> softmax reduces in-lane + 2 quad-shuffles)
// O^T = V^T·P^T (C col = l15 = qrow -> alpha rescale in-lane)
// LDS: QP (128x72) = Q staging then per-wave P; Ks/Vst (64x72 each) reused as O^T buffer.
__global__ __launch_bounds__(256) void attn_k(
    const unsigned short* __restrict__ qb,
    const unsigned short* __restrict__ kb,
    const unsigned short* __restrict__ vtb,
    float* __restrict__ x)
{
    __shared__ unsigned short SM[18432];
    unsigned short* QP  = SM;            // 128 x 72
    unsigned short* Ks  = SM + 9216;     // 64 x 72
    unsigned short* Vst = SM + 13824;    // 64 x 72
    unsigned short* Ob  = SM + 9216;     // 128 x 72 (aliases Ks+Vst, used after loop)

    const int t    = threadIdx.x;
    const int blk  = blockIdx.x;
    const int qt   = blk & 7;
    const int h    = (blk >> 3) & 15;
    const int b    = blk >> 7;
    const int w    = t >> 6;
    const int lane = t & 63;
    const int l15  = lane & 15;
    const int quad = lane >> 4;
    const int wrow = w * 32;             // this wave's q-row base (local)

    // ---- stage Q tile (128 rows x 64 d): 2 threads/row x 32 shorts ----
    {
        int r  = t >> 1;
        int dc = (t & 1) << 5;
        const uint4* src = (const uint4*)(qb + ((size_t)(b * 1024 + qt * 128 + r)) * 1024 + h * 64 + dc);
        uint4 u0 = src[0], u1 = src[1], u2 = src[2], u3 = src[3];
        *(uint4*)(QP + r * 72 + dc)      = u0;
        *(uint4*)(QP + r * 72 + dc + 8)  = u1;
        *(uint4*)(QP + r * 72 + dc + 16) = u2;
        *(uint4*)(QP + r * 72 + dc + 24) = u3;
    }
    __syncthreads();
    // Q frags: qf[nt2][kd]  (B-operand: n=l15=qrow, k=d)
    bf16x8 qf[2][2];
#pragma unroll
    for (int nt2 = 0; nt2 < 2; nt2++)
#pragma unroll
        for (int kd = 0; kd < 2; kd++)
            qf[nt2][kd] = *(const bf16x8*)(QP + (wrow + nt2 * 16 + l15) * 72 + kd * 32 + quad * 8);

    float m_s[2] = { -1e30f, -1e30f }, l_s[2] = { 0.f, 0.f };
    f32x4 O[2][4];
#pragma unroll
    for (int nt2 = 0; nt2 < 2; nt2++)
#pragma unroll
        for (int dt = 0; dt < 4; dt++) O[nt2][dt] = (f32x4)0.f;

    for (int kt = 0; kt < 16; ++kt) {
        __syncthreads();
        // ---- stage K tile [key][d] ----
        {
            int r  = t >> 2;
            int dc = (t & 3) << 4;
            const uint4* src = (const uint4*)(kb + ((size_t)(b * 1024 + kt * 64 + r)) * 1024 + h * 64 + dc);
            uint4 u0 = src[0], u1 = src[1];
            *(uint4*)(Ks + r * 72 + dc)     = u0;
            *(uint4*)(Ks + r * 72 + dc + 8) = u1;
        }
        // ---- stage V^T tile [d][key] ----
        {
            int d  = t >> 2;
            int kc = (t & 3) << 4;
            const uint4* src = (const uint4*)(vtb + (size_t)(h * 64 + d) * 8192 + b * 1024 + kt * 64 + kc);
            uint4 u0 = src[0], u1 = src[1];
            *(uint4*)(Vst + d * 72 + kc)     = u0;
            *(uint4*)(Vst + d * 72 + kc + 8) = u1;
        }
        __syncthreads();

        // ---- S^T = K Q^T : s[mt][nt2], key = mt*16+quad*4+r, qrow = nt2*16+l15 ----
        f32x4 s[4][2];
#pragma unroll
        for (int mt = 0; mt < 4; mt++) {
            bf16x8 kf0 = *(const bf16x8*)(Ks + (mt * 16 + l15) * 72 + quad * 8);
            bf16x8 kf1 = *(const bf16x8*)(Ks + (mt * 16 + l15) * 72 + 32 + quad * 8);
#pragma unroll
            for (int nt2 = 0; nt2 < 2; nt2++) {
                f32x4 a = (f32x4)0.f;
                a = __builtin_amdgcn_mfma_f32_16x16x32_bf16(kf0, qf[nt2][0], a, 0, 0, 0);
                a = __builtin_amdgcn_mfma_f32_16x16x32_bf16(kf1, qf[nt2][1], a, 0, 0, 0);
                s[mt][nt2] = a;
            }
        }

        // ---- online softmax (exp2 domain), per qrow = in-lane + 2 quad shuffles ----
#pragma unroll
        for (int nt2 = 0; nt2 < 2; nt2++) {
            float tm = -1e30f;
#pragma unroll
            for (int mt = 0; mt < 4; mt++) {
                f32x4 sv = s[mt][nt2];
                tm = fmaxf(tm, fmaxf(fmaxf(sv[0], sv[1]), fmaxf(sv[2], sv[3])));
            }
            tm = fmaxf(tm, __shfl_xor(tm, 16));
            tm = fmaxf(tm, __shfl_xor(tm, 32));
            float nm    = fmaxf(m_s[nt2], tm);
            float alpha = exp2f(m_s[nt2] - nm);
            float ls = 0.f;
#pragma unroll
            for (int mt = 0; mt < 4; mt++) {
#pragma unroll
                for (int r = 0; r < 4; r++) {
                    float p = exp2f(s[mt][nt2][r] - nm);
                    s[mt][nt2][r] = p;
                    ls += p;
                }
            }
            ls += __shfl_xor(ls, 16);
            ls += __shfl_xor(ls, 32);
            l_s[nt2] = l_s[nt2] * alpha + ls;
            m_s[nt2] = nm;
#pragma unroll
            for (int dt = 0; dt < 4; dt++) O[nt2][dt] *= alpha;
        }

        // ---- P^T -> LDS [qrow][key] (per-wave region, b64 packed writes) ----
#pragma unroll
        for (int nt2 = 0; nt2 < 2; nt2++) {
#pragma unroll
            for (int mt = 0; mt < 4; mt++) {
                uint2 pk = pk4(s[mt][nt2][0], s[mt][nt2][1], s[mt][nt2][2], s[mt][nt2][3]);
                *(uint2*)(QP + (wrow + nt2 * 16 + l15) * 72 + mt * 16 + quad * 4) = pk;
            }
        }
        bf16x8 pf[2][2];
#pragma unroll
        for (int nt2 = 0; nt2 < 2; nt2++)
#pragma unroll
            for (int kc = 0; kc < 2; kc++)
                pf[nt2][kc] = *(const bf16x8*)(QP + (wrow + nt2 * 16 + l15) * 72 + kc * 32 + quad * 8);

        // ---- O^T += V^T P^T : O row = d = dt*16+quad*4+r, col = qrow = nt2*16+l15 ----
#pragma unroll
        for (int dt = 0; dt < 4; dt++) {
            bf16x8 vf0 = *(const bf16x8*)(Vst + (dt * 16 + l15) * 72 + quad * 8);
            bf16x8 vf1 = *(const bf16x8*)(Vst + (dt * 16 + l15) * 72 + 32 + quad * 8);
#pragma unroll
            for (int nt2 = 0; nt2 < 2; nt2++) {
                O[nt2][dt] = __builtin_amdgcn_mfma_f32_16x16x32_bf16(vf0, pf[nt2][0], O[nt2][dt], 0, 0, 0);
                O[nt2][dt] = __builtin_amdgcn_mfma_f32_16x16x32_bf16(vf1, pf[nt2][1], O[nt2][dt], 0, 0, 0);
            }
        }
    }

    // ---- O^T -> LDS (bf16) to transpose back; then coalesced residual add ----
    __syncthreads();
    {
        float inv0 = 1.f / l_s[0], inv1 = 1.f / l_s[1];
#pragma unroll
        for (int nt2 = 0; nt2 < 2; nt2++) {
            float inv = (nt2 == 0) ? inv0 : inv1;
#pragma unroll
            for (int dt = 0; dt < 4; dt++) {
                uint2 pk = pk4(O[nt2][dt][0] * inv, O[nt2][dt][1] * inv,
                               O[nt2][dt][2] * inv, O[nt2][dt][3] * inv);
                *(uint2*)(Ob + (wrow + nt2 * 16 + l15) * 72 + dt * 16 + quad * 4) = pk;
            }
        }
    }
    __syncthreads();
    {
        int r0 = t >> 2;                 // rows r0 and r0+64
        int qo = (t & 3) << 4;           // 16-d chunk
#pragma unroll
        for (int half = 0; half < 2; half++) {
            int r = r0 + half * 64;
            float* xp = x + ((size_t)(b * 1024 + qt * 128 + r)) * 1024 + h * 64 + qo;
            const unsigned short* op = Ob + r * 72 + qo;
#pragma unroll
            for (int j = 0; j < 2; j++) {
                uint4 u = *(const uint4*)(op + j * 8);
                f32x4 xv0 = *(f32x4*)(xp + j * 8);
                f32x4 xv1 = *(f32x4*)(xp + j * 8 + 4);
                xv0[0] += b2f((unsigned short)(u.x & 0xffff));
                xv0[1] += b2f((unsigned short)(u.x >> 16));
                xv0[2] += b2f((unsigned short)(u.y & 0xffff));
                xv0[3] += b2f((unsigned short)(u.y >> 16));
                xv1[0] += b2f((unsigned short)(u.z & 0xffff));
                xv1[1] += b2f((unsigned short)(u.z >> 16));
                xv1[2] += b2f((unsigned short)(u.w & 0xffff));
                xv1[3] += b2f((unsigned short)(u.w >> 16));
                *(f32x4*)(xp + j * 8)     = xv0;
                *(f32x4*)(xp + j * 8 + 4) = xv1;
            }
        }
    }
}

// ---------------- launch ----------------
extern "C" void kernel_launch(void* const* d_in, const int* in_sizes, int n_in,
                              void* d_out, int out_size, void* d_ws, size_t ws_size,
                              hipStream_t stream)
{
    (void)in_sizes; (void)n_in; (void)out_size; (void)ws_size;
    const float* x_in  = (const float*)d_in[0];
    const float* Wq    = (const float*)d_in[1];
    const float* bq    = (const float*)d_in[2];
    const float* Wk    = (const float*)d_in[3];
    const float* bk    = (const float*)d_in[4];
    const float* Wv    = (const float*)d_in[5];
    const float* bv    = (const float*)d_in[6];
    const float* W1    = (const float*)d_in[7];
    const float* b1    = (const float*)d_in[8];
    const float* W2    = (const float*)d_in[9];
    const float* b2    = (const float*)d_in[10];
    const float* gamma = (const float*)d_in[11];
    const float* beta  = (const float*)d_in[12];

    char* base = (char*)d_ws;
    float*          xf   = (float*)(base);                               // 32 MB
    unsigned short* xn   = (unsigned short*)(base + 33554432);           // 16 MB
    unsigned short* qbuf = (unsigned short*)(base + 50331648);
    unsigned short* kbuf = (unsigned short*)(base + 50331648 + 16777216);
    unsigned short* vtb  = (unsigned short*)(base + 50331648 + 33554432); // V^T [1024][8192]
    unsigned short* h1   = (unsigned short*)(base + 50331648);           // 64 MB (aliases q/k/vt)
    char* wbase = base + 50331648 + 67108864;
    unsigned short* WqT = (unsigned short*)(wbase);
    unsigned short* WkT = (unsigned short*)(wbase + 2097152);
    unsigned short* WvT = (unsigned short*)(wbase + 4194304);
    unsigned short* W1T = (unsigned short*)(wbase + 6291456);
    unsigned short* W2T = (unsigned short*)(wbase + 14680064);

    transpose_f32_to_bf16<<<dim3(32, 32),  256, 0, stream>>>(Wq, WqT, 1024, 1024);
    transpose_f32_to_bf16<<<dim3(32, 32),  256, 0, stream>>>(Wk, WkT, 1024, 1024);
    transpose_f32_to_bf16<<<dim3(32, 32),  256, 0, stream>>>(Wv, WvT, 1024, 1024);
    transpose_f32_to_bf16<<<dim3(128, 32), 256, 0, stream>>>(W1, W1T, 1024, 4096);
    transpose_f32_to_bf16<<<dim3(32, 128), 256, 0, stream>>>(W2, W2T, 4096, 1024);
    copy_f32<<<4096, 256, 0, stream>>>(x_in, xf);

    for (int layer = 0; layer < 6; ++layer) {
        layernorm_k<<<8192, 256, 0, stream>>>(xf, gamma, beta, xn);
        gemm_bt<4><<<dim3(8, 64),  256, 0, stream>>>(xn, WqT, bq, qbuf, 8192, 1024, 1024);
        gemm_bt<0><<<dim3(8, 64),  256, 0, stream>>>(xn, WkT, bk, kbuf, 8192, 1024, 1024);
        gemm_bt<3><<<dim3(64, 8),  256, 0, stream>>>(WvT, xn, bv, vtb, 1024, 8192, 1024);
        attn_k<<<1024, 256, 0, stream>>>(qbuf, kbuf, vtb, xf);
        layernorm_k<<<8192, 256, 0, stream>>>(xf, gamma, beta, xn);
        gemm_bt<1><<<dim3(32, 64), 256, 0, stream>>>(xn, W1T, b1, h1, 8192, 4096, 1024);
        gemm_bt<2><<<dim3(8, 64),  256, 0, stream>>>(h1, W2T, b2, xf, 8192, 1024, 4096);
    }
    copy_f32<<<4096, 256, 0, stream>>>(xf, (float*)d_out);
}

// Round 8
// 2763.530 us; speedup vs baseline: 3.5570x; 1.0027x over previous
//
#include <hip/hip_runtime.h>
#include <cstdint>
#include <cmath>

typedef short bf16x8 __attribute__((ext_vector_type(8)));
typedef float f32x4 __attribute__((ext_vector_type(4)));

#define AS_GLOBAL(p) (const __attribute__((address_space(1))) void*)(p)
#define AS_LDS(p)    (__attribute__((address_space(3))) void*)(p)

// SCALE * log2(e) folded into Q epilogue: 2^-5 * 1.44269504
#define QSCALE 0.04508422002778f

__device__ inline float b2f(unsigned short u) {
    union { unsigned int i; float f; } c; c.i = ((unsigned int)u) << 16; return c.f;
}
__device__ inline unsigned short f2b(float f) {
    return (unsigned short)((__float_as_uint(f) + 0x8000u) >> 16);
}
// pack 4 floats -> 4 bf16 (round-half-up) in a uint2
__device__ inline uint2 pk4(float a, float b, float c, float d) {
    unsigned ua = __float_as_uint(a) + 0x8000u;
    unsigned ub = __float_as_uint(b) + 0x8000u;
    unsigned uc = __float_as_uint(c) + 0x8000u;
    unsigned ud = __float_as_uint(d) + 0x8000u;
    uint2 r;
    r.x = (ua >> 16) | (ub & 0xffff0000u);
    r.y = (uc >> 16) | (ud & 0xffff0000u);
    return r;
}

// ---------------- weight transpose+cast: W[K][N] (f32) -> Wt[N][K] (bf16) ----------------
__global__ __launch_bounds__(256) void transpose_f32_to_bf16(
    const float* __restrict__ W, unsigned short* __restrict__ Wt, int K, int N)
{
    __shared__ unsigned short sh[32][33];
    int n0 = blockIdx.x * 32;
    int k0 = blockIdx.y * 32;
    int tr = threadIdx.x >> 5;
    int tc = threadIdx.x & 31;
#pragma unroll
    for (int i = 0; i < 4; i++)
        sh[tr + i * 8][tc] = f2b(W[(size_t)(k0 + tr + i * 8) * N + n0 + tc]);
    __syncthreads();
#pragma unroll
    for (int i = 0; i < 4; i++)
        Wt[(size_t)(n0 + tr + i * 8) * K + k0 + tc] = sh[tc][tr + i * 8];
}

// ---------------- fp32 copy (8 elems/thread) ----------------
__global__ __launch_bounds__(256) void copy_f32(const float* __restrict__ in,
                                                float* __restrict__ out)
{
    size_t i = ((size_t)blockIdx.x * 256 + threadIdx.x) * 8;
    f32x4 a = *(const f32x4*)(in + i);
    f32x4 b = *(const f32x4*)(in + i + 4);
    *(f32x4*)(out + i) = a;
    *(f32x4*)(out + i + 4) = b;
}

// ---------------- layernorm: fp32 in -> bf16 out ----------------
__global__ __launch_bounds__(256) void layernorm_k(
    const float* __restrict__ x, const float* __restrict__ gamma,
    const float* __restrict__ beta, unsigned short* __restrict__ out)
{
    int row = blockIdx.x;
    int t = threadIdx.x;
    f32x4 v = *(const f32x4*)(x + (size_t)row * 1024 + t * 4);
    float s  = v[0] + v[1] + v[2] + v[3];
    float s2 = v[0]*v[0] + v[1]*v[1] + v[2]*v[2] + v[3]*v[3];
#pragma unroll
    for (int off = 32; off >= 1; off >>= 1) {
        s  += __shfl_xor(s,  off);
        s2 += __shfl_xor(s2, off);
    }
    __shared__ float red[8];
    int w = t >> 6;
    if ((t & 63) == 0) { red[w] = s; red[4 + w] = s2; }
    __syncthreads();
    s  = red[0] + red[1] + red[2] + red[3];
    s2 = red[4] + red[5] + red[6] + red[7];
    float mu  = s * (1.f / 1024.f);
    float var = s2 * (1.f / 1024.f) - mu * mu;
    float rs  = rsqrtf(var + 1e-5f);
    int c = t * 4;
    f32x4 g = *(const f32x4*)(gamma + c);
    f32x4 be = *(const f32x4*)(beta + c);
    unsigned int lo, hi;
    {
        float o0 = (v[0] - mu) * rs * g[0] + be[0];
        float o1 = (v[1] - mu) * rs * g[1] + be[1];
        float o2 = (v[2] - mu) * rs * g[2] + be[2];
        float o3 = (v[3] - mu) * rs * g[3] + be[3];
        lo = (unsigned)f2b(o0) | ((unsigned)f2b(o1) << 16);
        hi = (unsigned)f2b(o2) | ((unsigned)f2b(o3) << 16);
    }
    uint2 pk; pk.x = lo; pk.y = hi;
    *(uint2*)(out + (size_t)row * 1024 + c) = pk;
}

// ---------------- MFMA GEMM: C[M][N] = A[M][K](bf16) * Bt[N][K]^T(bf16) + bias(f32) ----------------
// 1-D grid, XCD-aware swizzle: block i -> XCD r=i&7 (dispatch round-robin heuristic);
// within an XCD the sequence iterates all n-blocks for a fixed m-block, so the A
// row-block (<=1 MB) stays in that XCD's 4 MB L2 across the n-sweep.
// NBXL = log2(N/128). Requires M multiple of 1024 (m-blocks divisible by 8).
// MODE 0: bf16 out = v + bias[col]
// MODE 1: bf16 out = gelu_exact(v + bias[col])
// MODE 2: f32 out += v + bias[col]     (residual add)
// MODE 3: bf16 out = v + bias[row]     (V^T GEMM: bias indexed by output row=dim)
// MODE 4: bf16 out = (v + bias[col]) * QSCALE   (Q GEMM, softmax pre-scale)
template<int MODE, int NBXL>
__global__ __launch_bounds__(256) void gemm_bt(
    const unsigned short* __restrict__ A,
    const unsigned short* __restrict__ Bt,
    const float* __restrict__ bias,
    void* __restrict__ outp,
    int M, int N, int K)
{
    __shared__ unsigned short As[128 * 32];
    __shared__ unsigned short Bs[128 * 32];
    const int t = threadIdx.x;

    // XCD-aware block swizzle
    const int bi   = blockIdx.x;
    const int xcd  = bi & 7;
    const int j    = bi >> 3;
    const int nby8 = M >> 10;                    // (M/128)/8
    const int m_idx = xcd * nby8 + (j >> NBXL);
    const int n_idx = j & ((1 << NBXL) - 1);
    const int n0 = n_idx * 128;
    const int m0 = m_idx * 128;

    const int lane = t & 63;
    const int wave = t >> 6;
    const int wm = (wave >> 1) * 64;
    const int wn = (wave & 1) * 64;
    const int lm = lane & 15;
    const int q  = lane >> 4;

    const int pos0 = wave * 128 + lane;
    const int row0 = pos0 >> 2;
    const int row1 = (pos0 + 64) >> 2;
    const int cg0  = (pos0 & 3) << 3;
    const int ldsb = wave * 1024;

    f32x4 acc[4][4];
#pragma unroll
    for (int i = 0; i < 4; i++)
#pragma unroll
        for (int n = 0; n < 4; n++) acc[i][n] = (f32x4)0.f;

    for (int k0 = 0; k0 < K; k0 += 32) {
        __syncthreads();
        {
            const unsigned short* ga0 = A  + (size_t)(m0 + row0) * K + k0 + cg0;
            const unsigned short* ga1 = A  + (size_t)(m0 + row1) * K + k0 + cg0;
            const unsigned short* gb0 = Bt + (size_t)(n0 + row0) * K + k0 + cg0;
            const unsigned short* gb1 = Bt + (size_t)(n0 + row1) * K + k0 + cg0;
            __builtin_amdgcn_global_load_lds(AS_GLOBAL(ga0), AS_LDS(As + ldsb),       16, 0, 0);
            __builtin_amdgcn_global_load_lds(AS_GLOBAL(ga1), AS_LDS(As + ldsb + 512), 16, 0, 0);
            __builtin_amdgcn_global_load_lds(AS_GLOBAL(gb0), AS_LDS(Bs + ldsb),       16, 0, 0);
            __builtin_amdgcn_global_load_lds(AS_GLOBAL(gb1), AS_LDS(Bs + ldsb + 512), 16, 0, 0);
        }
        __syncthreads();
        bf16x8 af[4], bfr[4];
#pragma unroll
        for (int i = 0; i < 4; i++)
            af[i] = *(const bf16x8*)(As + (wm + i * 16 + lm) * 32 + q * 8);
#pragma unroll
        for (int n = 0; n < 4; n++)
            bfr[n] = *(const bf16x8*)(Bs + (wn + n * 16 + lm) * 32 + q * 8);
#pragma unroll
        for (int i = 0; i < 4; i++)
#pragma unroll
            for (int n = 0; n < 4; n++)
                acc[i][n] = __builtin_amdgcn_mfma_f32_16x16x32_bf16(af[i], bfr[n], acc[i][n], 0, 0, 0);
    }

#pragma unroll
    for (int i = 0; i < 4; i++) {
#pragma unroll
        for (int n = 0; n < 4; n++) {
            int gc = n0 + wn + n * 16 + lm;
            float bv = (MODE == 3) ? 0.f : bias[gc];
#pragma unroll
            for (int r = 0; r < 4; r++) {
                int gr = m0 + wm + i * 16 + q * 4 + r;
                float v = acc[i][n][r] + ((MODE == 3) ? bias[gr] : bv);
                if (MODE == 0) {
                    ((unsigned short*)outp)[(size_t)gr * N + gc] = f2b(v);
                } else if (MODE == 1) {
                    float g = 0.5f * v * (1.f + erff(v * 0.70710678118654752f));
                    ((unsigned short*)outp)[(size_t)gr * N + gc] = f2b(g);
                } else if (MODE == 2) {
                    ((float*)outp)[(size_t)gr * N + gc] += v;
                } else if (MODE == 3) {
                    ((unsigned short*)outp)[(size_t)gr * N + gc] = f2b(v);
                } else {
                    ((unsigned short*)outp)[(size_t)gr * N + gc] = f2b(v * QSCALE);
                }
            }
        }
    }
}

// ---------------- MFMA flash attention v3: 128 q-rows/block, S^T orientation ----------------
// grid = 1024: blk = ((b*16 + h)*8 + qt); 4 waves x 32 q-rows.
__global__ __launch_bounds__(256) void attn_k(
    const unsigned short* __restrict__ qb,
    const unsigned short* __restrict__ kb,
    const unsigned short* __restrict__ vtb,
    float* __restrict__ x)
{
    __shared__ unsigned short SM[18432];
    unsigned short* QP  = SM;            // 128 x 72
    unsigned short* Ks  = SM + 9216;     // 64 x 72
    unsigned short* Vst = SM + 13824;    // 64 x 72
    unsigned short* Ob  = SM + 9216;     // 128 x 72 (aliases Ks+Vst, used after loop)

    const int t    = threadIdx.x;
    const int blk  = blockIdx.x;
    const int qt   = blk & 7;
    const int h    = (blk >> 3) & 15;
    const int b    = blk >> 7;
    const int w    = t >> 6;
    const int lane = t & 63;
    const int l15  = lane & 15;
    const int quad = lane >> 4;
    const int wrow = w * 32;

    // ---- stage Q tile (128 rows x 64 d) ----
    {
        int r  = t >> 1;
        int dc = (t & 1) << 5;
        const uint4* src = (const uint4*)(qb + ((size_t)(b * 1024 + qt * 128 + r)) * 1024 + h * 64 + dc);
        uint4 u0 = src[0], u1 = src[1], u2 = src[2], u3 = src[3];
        *(uint4*)(QP + r * 72 + dc)      = u0;
        *(uint4*)(QP + r * 72 + dc + 8)  = u1;
        *(uint4*)(QP + r * 72 + dc + 16) = u2;
        *(uint4*)(QP + r * 72 + dc + 24) = u3;
    }
    __syncthreads();
    bf16x8 qf[2][2];
#pragma unroll
    for (int nt2 = 0; nt2 < 2; nt2++)
#pragma unroll
        for (int kd = 0; kd < 2; kd++)
            qf[nt2][kd] = *(const bf16x8*)(QP + (wrow + nt2 * 16 + l15) * 72 + kd * 32 + quad * 8);

    float m_s[2] = { -1e30f, -1e30f }, l_s[2] = { 0.f, 0.f };
    f32x4 O[2][4];
#pragma unroll
    for (int nt2 = 0; nt2 < 2; nt2++)
#pragma unroll
        for (int dt = 0; dt < 4; dt++) O[nt2][dt] = (f32x4)0.f;

    for (int kt = 0; kt < 16; ++kt) {
        __syncthreads();
        {
            int r  = t >> 2;
            int dc = (t & 3) << 4;
            const uint4* src = (const uint4*)(kb + ((size_t)(b * 1024 + kt * 64 + r)) * 1024 + h * 64 + dc);
            uint4 u0 = src[0], u1 = src[1];
            *(uint4*)(Ks + r * 72 + dc)     = u0;
            *(uint4*)(Ks + r * 72 + dc + 8) = u1;
        }
        {
            int d  = t >> 2;
            int kc = (t & 3) << 4;
            const uint4* src = (const uint4*)(vtb + (size_t)(h * 64 + d) * 8192 + b * 1024 + kt * 64 + kc);
            uint4 u0 = src[0], u1 = src[1];
            *(uint4*)(Vst + d * 72 + kc)     = u0;
            *(uint4*)(Vst + d * 72 + kc + 8) = u1;
        }
        __syncthreads();

        // ---- S^T = K Q^T ----
        f32x4 s[4][2];
#pragma unroll
        for (int mt = 0; mt < 4; mt++) {
            bf16x8 kf0 = *(const bf16x8*)(Ks + (mt * 16 + l15) * 72 + quad * 8);
            bf16x8 kf1 = *(const bf16x8*)(Ks + (mt * 16 + l15) * 72 + 32 + quad * 8);
#pragma unroll
            for (int nt2 = 0; nt2 < 2; nt2++) {
                f32x4 a = (f32x4)0.f;
                a = __builtin_amdgcn_mfma_f32_16x16x32_bf16(kf0, qf[nt2][0], a, 0, 0, 0);
                a = __builtin_amdgcn_mfma_f32_16x16x32_bf16(kf1, qf[nt2][1], a, 0, 0, 0);
                s[mt][nt2] = a;
            }
        }

        // ---- online softmax (exp2 domain) ----
#pragma unroll
        for (int nt2 = 0; nt2 < 2; nt2++) {
            float tm = -1e30f;
#pragma unroll
            for (int mt = 0; mt < 4; mt++) {
                f32x4 sv = s[mt][nt2];
                tm = fmaxf(tm, fmaxf(fmaxf(sv[0], sv[1]), fmaxf(sv[2], sv[3])));
            }
            tm = fmaxf(tm, __shfl_xor(tm, 16));
            tm = fmaxf(tm, __shfl_xor(tm, 32));
            float nm    = fmaxf(m_s[nt2], tm);
            float alpha = exp2f(m_s[nt2] - nm);
            float ls = 0.f;
#pragma unroll
            for (int mt = 0; mt < 4; mt++) {
#pragma unroll
                for (int r = 0; r < 4; r++) {
                    float p = exp2f(s[mt][nt2][r] - nm);
                    s[mt][nt2][r] = p;
                    ls += p;
                }
            }
            ls += __shfl_xor(ls, 16);
            ls += __shfl_xor(ls, 32);
            l_s[nt2] = l_s[nt2] * alpha + ls;
            m_s[nt2] = nm;
#pragma unroll
            for (int dt = 0; dt < 4; dt++) O[nt2][dt] *= alpha;
        }

        // ---- P^T -> LDS [qrow][key] ----
#pragma unroll
        for (int nt2 = 0; nt2 < 2; nt2++) {
#pragma unroll
            for (int mt = 0; mt < 4; mt++) {
                uint2 pk = pk4(s[mt][nt2][0], s[mt][nt2][1], s[mt][nt2][2], s[mt][nt2][3]);
                *(uint2*)(QP + (wrow + nt2 * 16 + l15) * 72 + mt * 16 + quad * 4) = pk;
            }
        }
        bf16x8 pf[2][2];
#pragma unroll
        for (int nt2 = 0; nt2 < 2; nt2++)
#pragma unroll
            for (int kc = 0; kc < 2; kc++)
                pf[nt2][kc] = *(const bf16x8*)(QP + (wrow + nt2 * 16 + l15) * 72 + kc * 32 + quad * 8);

        // ---- O^T += V^T P^T ----
#pragma unroll
        for (int dt = 0; dt < 4; dt++) {
            bf16x8 vf0 = *(const bf16x8*)(Vst + (dt * 16 + l15) * 72 + quad * 8);
            bf16x8 vf1 = *(const bf16x8*)(Vst + (dt * 16 + l15) * 72 + 32 + quad * 8);
#pragma unroll
            for (int nt2 = 0; nt2 < 2; nt2++) {
                O[nt2][dt] = __builtin_amdgcn_mfma_f32_16x16x32_bf16(vf0, pf[nt2][0], O[nt2][dt], 0, 0, 0);
                O[nt2][dt] = __builtin_amdgcn_mfma_f32_16x16x32_bf16(vf1, pf[nt2][1], O[nt2][dt], 0, 0, 0);
            }
        }
    }

    // ---- O^T -> LDS (bf16); coalesced residual add ----
    __syncthreads();
    {
        float inv0 = 1.f / l_s[0], inv1 = 1.f / l_s[1];
#pragma unroll
        for (int nt2 = 0; nt2 < 2; nt2++) {
            float inv = (nt2 == 0) ? inv0 : inv1;
#pragma unroll
            for (int dt = 0; dt < 4; dt++) {
                uint2 pk = pk4(O[nt2][dt][0] * inv, O[nt2][dt][1] * inv,
                               O[nt2][dt][2] * inv, O[nt2][dt][3] * inv);
                *(uint2*)(Ob + (wrow + nt2 * 16 + l15) * 72 + dt * 16 + quad * 4) = pk;
            }
        }
    }
    __syncthreads();
    {
        int r0 = t >> 2;
        int qo = (t & 3) << 4;
#pragma unroll
        for (int half = 0; half < 2; half++) {
            int r = r0 + half * 64;
            float* xp = x + ((size_t)(b * 1024 + qt * 128 + r)) * 1024 + h * 64 + qo;
            const unsigned short* op = Ob + r * 72 + qo;
#pragma unroll
            for (int j = 0; j < 2; j++) {
                uint4 u = *(const uint4*)(op + j * 8);
                f32x4 xv0 = *(f32x4*)(xp + j * 8);
                f32x4 xv1 = *(f32x4*)(xp + j * 8 + 4);
                xv0[0] += b2f((unsigned short)(u.x & 0xffff));
                xv0[1] += b2f((unsigned short)(u.x >> 16));
                xv0[2] += b2f((unsigned short)(u.y & 0xffff));
                xv0[3] += b2f((unsigned short)(u.y >> 16));
                xv1[0] += b2f((unsigned short)(u.z & 0xffff));
                xv1[1] += b2f((unsigned short)(u.z >> 16));
                xv1[2] += b2f((unsigned short)(u.w & 0xffff));
                xv1[3] += b2f((unsigned short)(u.w >> 16));
                *(f32x4*)(xp + j * 8)     = xv0;
                *(f32x4*)(xp + j * 8 + 4) = xv1;
            }
        }
    }
}

// ---------------- launch ----------------
extern "C" void kernel_launch(void* const* d_in, const int* in_sizes, int n_in,
                              void* d_out, int out_size, void* d_ws, size_t ws_size,
                              hipStream_t stream)
{
    (void)in_sizes; (void)n_in; (void)out_size; (void)ws_size;
    const float* x_in  = (const float*)d_in[0];
    const float* Wq    = (const float*)d_in[1];
    const float* bq    = (const float*)d_in[2];
    const float* Wk    = (const float*)d_in[3];
    const float* bk    = (const float*)d_in[4];
    const float* Wv    = (const float*)d_in[5];
    const float* bv    = (const float*)d_in[6];
    const float* W1    = (const float*)d_in[7];
    const float* b1    = (const float*)d_in[8];
    const float* W2    = (const float*)d_in[9];
    const float* b2    = (const float*)d_in[10];
    const float* gamma = (const float*)d_in[11];
    const float* beta  = (const float*)d_in[12];

    char* base = (char*)d_ws;
    float*          xf   = (float*)(base);                               // 32 MB
    unsigned short* xn   = (unsigned short*)(base + 33554432);           // 16 MB
    unsigned short* qbuf = (unsigned short*)(base + 50331648);
    unsigned short* kbuf = (unsigned short*)(base + 50331648 + 16777216);
    unsigned short* vtb  = (unsigned short*)(base + 50331648 + 33554432); // V^T [1024][8192]
    unsigned short* h1   = (unsigned short*)(base + 50331648);           // 64 MB (aliases q/k/vt)
    char* wbase = base + 50331648 + 67108864;
    unsigned short* WqT = (unsigned short*)(wbase);
    unsigned short* WkT = (unsigned short*)(wbase + 2097152);
    unsigned short* WvT = (unsigned short*)(wbase + 4194304);
    unsigned short* W1T = (unsigned short*)(wbase + 6291456);
    unsigned short* W2T = (unsigned short*)(wbase + 14680064);

    transpose_f32_to_bf16<<<dim3(32, 32),  256, 0, stream>>>(Wq, WqT, 1024, 1024);
    transpose_f32_to_bf16<<<dim3(32, 32),  256, 0, stream>>>(Wk, WkT, 1024, 1024);
    transpose_f32_to_bf16<<<dim3(32, 32),  256, 0, stream>>>(Wv, WvT, 1024, 1024);
    transpose_f32_to_bf16<<<dim3(128, 32), 256, 0, stream>>>(W1, W1T, 1024, 4096);
    transpose_f32_to_bf16<<<dim3(32, 128), 256, 0, stream>>>(W2, W2T, 4096, 1024);
    copy_f32<<<4096, 256, 0, stream>>>(x_in, xf);

    for (int layer = 0; layer < 6; ++layer) {
        layernorm_k<<<8192, 256, 0, stream>>>(xf, gamma, beta, xn);
        // QKV: M=8192 N=1024 (nbx=8, NBXL=3), 512 blocks
        gemm_bt<4, 3><<<512,  256, 0, stream>>>(xn, WqT, bq, qbuf, 8192, 1024, 1024);
        gemm_bt<0, 3><<<512,  256, 0, stream>>>(xn, WkT, bk, kbuf, 8192, 1024, 1024);
        // V^T: M=1024 N=8192 (nbx=64, NBXL=6), 512 blocks
        gemm_bt<3, 6><<<512,  256, 0, stream>>>(WvT, xn, bv, vtb, 1024, 8192, 1024);
        attn_k<<<1024, 256, 0, stream>>>(qbuf, kbuf, vtb, xf);
        layernorm_k<<<8192, 256, 0, stream>>>(xf, gamma, beta, xn);
        // MLP up: M=8192 N=4096 (nbx=32, NBXL=5), 2048 blocks
        gemm_bt<1, 5><<<2048, 256, 0, stream>>>(xn, W1T, b1, h1, 8192, 4096, 1024);
        // MLP down: M=8192 N=1024 (nbx=8, NBXL=3), 512 blocks
        gemm_bt<2, 3><<<512,  256, 0, stream>>>(h1, W2T, b2, xf, 8192, 1024, 4096);
    }
    copy_f32<<<4096, 256, 0, stream>>>(xf, (float*)d_out);
}

// Round 9
// 2582.462 us; speedup vs baseline: 3.8063x; 1.0701x over previous
//
#include <hip/hip_runtime.h>
#include <cstdint>
#include <cmath>

typedef short bf16x8 __attribute__((ext_vector_type(8)));
typedef float f32x4 __attribute__((ext_vector_type(4)));

#define AS_GLOBAL(p) (const __attribute__((address_space(1))) void*)(p)
#define AS_LDS(p)    (__attribute__((address_space(3))) void*)(p)

// SCALE * log2(e) folded into Q epilogue: 2^-5 * 1.44269504
#define QSCALE 0.04508422002778f

__device__ inline float b2f(unsigned short u) {
    union { unsigned int i; float f; } c; c.i = ((unsigned int)u) << 16; return c.f;
}
__device__ inline unsigned short f2b(float f) {
    return (unsigned short)((__float_as_uint(f) + 0x8000u) >> 16);
}
// pack 4 floats -> 4 bf16 (round-half-up) in a uint2
__device__ inline uint2 pk4(float a, float b, float c, float d) {
    unsigned ua = __float_as_uint(a) + 0x8000u;
    unsigned ub = __float_as_uint(b) + 0x8000u;
    unsigned uc = __float_as_uint(c) + 0x8000u;
    unsigned ud = __float_as_uint(d) + 0x8000u;
    uint2 r;
    r.x = (ua >> 16) | (ub & 0xffff0000u);
    r.y = (uc >> 16) | (ud & 0xffff0000u);
    return r;
}
// fast GELU: x * sigmoid(1.5957691x + 0.071354816x^3), evaluated in exp2 domain.
// max abs err vs exact erf-GELU ~5e-4 (far below bf16 rounding of the output).
__device__ inline float fast_gelu(float x) {
    float arg = -x * (2.30223674f + 0.10294946f * x * x);
    float t = exp2f(arg);
    return x * __builtin_amdgcn_rcpf(1.f + t);
}

// ---------------- weight transpose+cast: W[K][N] (f32) -> Wt[N][K] (bf16) ----------------
__global__ __launch_bounds__(256) void transpose_f32_to_bf16(
    const float* __restrict__ W, unsigned short* __restrict__ Wt, int K, int N)
{
    __shared__ unsigned short sh[32][33];
    int n0 = blockIdx.x * 32;
    int k0 = blockIdx.y * 32;
    int tr = threadIdx.x >> 5;
    int tc = threadIdx.x & 31;
#pragma unroll
    for (int i = 0; i < 4; i++)
        sh[tr + i * 8][tc] = f2b(W[(size_t)(k0 + tr + i * 8) * N + n0 + tc]);
    __syncthreads();
#pragma unroll
    for (int i = 0; i < 4; i++)
        Wt[(size_t)(n0 + tr + i * 8) * K + k0 + tc] = sh[tc][tr + i * 8];
}

// ---------------- bias concat: bqk = [bq | bk] ----------------
__global__ __launch_bounds__(256) void concat_bias(const float* __restrict__ bq,
                                                   const float* __restrict__ bk,
                                                   float* __restrict__ bqk)
{
    int i = blockIdx.x * 256 + threadIdx.x;
    bqk[i] = (i < 1024) ? bq[i] : bk[i - 1024];
}

// ---------------- fp32 copy (8 elems/thread) ----------------
__global__ __launch_bounds__(256) void copy_f32(const float* __restrict__ in,
                                                float* __restrict__ out)
{
    size_t i = ((size_t)blockIdx.x * 256 + threadIdx.x) * 8;
    f32x4 a = *(const f32x4*)(in + i);
    f32x4 b = *(const f32x4*)(in + i + 4);
    *(f32x4*)(out + i) = a;
    *(f32x4*)(out + i + 4) = b;
}

// ---------------- layernorm: fp32 in -> bf16 out ----------------
__global__ __launch_bounds__(256) void layernorm_k(
    const float* __restrict__ x, const float* __restrict__ gamma,
    const float* __restrict__ beta, unsigned short* __restrict__ out)
{
    int row = blockIdx.x;
    int t = threadIdx.x;
    f32x4 v = *(const f32x4*)(x + (size_t)row * 1024 + t * 4);
    float s  = v[0] + v[1] + v[2] + v[3];
    float s2 = v[0]*v[0] + v[1]*v[1] + v[2]*v[2] + v[3]*v[3];
#pragma unroll
    for (int off = 32; off >= 1; off >>= 1) {
        s  += __shfl_xor(s,  off);
        s2 += __shfl_xor(s2, off);
    }
    __shared__ float red[8];
    int w = t >> 6;
    if ((t & 63) == 0) { red[w] = s; red[4 + w] = s2; }
    __syncthreads();
    s  = red[0] + red[1] + red[2] + red[3];
    s2 = red[4] + red[5] + red[6] + red[7];
    float mu  = s * (1.f / 1024.f);
    float var = s2 * (1.f / 1024.f) - mu * mu;
    float rs  = rsqrtf(var + 1e-5f);
    int c = t * 4;
    f32x4 g = *(const f32x4*)(gamma + c);
    f32x4 be = *(const f32x4*)(beta + c);
    unsigned int lo, hi;
    {
        float o0 = (v[0] - mu) * rs * g[0] + be[0];
        float o1 = (v[1] - mu) * rs * g[1] + be[1];
        float o2 = (v[2] - mu) * rs * g[2] + be[2];
        float o3 = (v[3] - mu) * rs * g[3] + be[3];
        lo = (unsigned)f2b(o0) | ((unsigned)f2b(o1) << 16);
        hi = (unsigned)f2b(o2) | ((unsigned)f2b(o3) << 16);
    }
    uint2 pk; pk.x = lo; pk.y = hi;
    *(uint2*)(out + (size_t)row * 1024 + c) = pk;
}

// ---------------- MFMA GEMM: C[M][N] = A[M][K](bf16) * Bt[N][K]^T(bf16) + bias(f32) ----------------
// 1-D grid, XCD-aware swizzle (block i -> XCD i&7; n-sweep inside m-block).
// NBXL = log2(N/128). Requires M multiple of 1024.
// MODE 1: bf16 out = fast_gelu(v + bias[col])
// MODE 2: f32 out += v + bias[col]     (residual add)
// MODE 3: bf16 out = v + bias[row]     (V^T GEMM: bias indexed by output row=dim)
// MODE 5: bf16 out = (v + bias[col]) * (col<1024 ? QSCALE : 1)   (fused QK GEMM)
template<int MODE, int NBXL>
__global__ __launch_bounds__(256) void gemm_bt(
    const unsigned short* __restrict__ A,
    const unsigned short* __restrict__ Bt,
    const float* __restrict__ bias,
    void* __restrict__ outp,
    int M, int N, int K)
{
    __shared__ unsigned short As[128 * 32];
    __shared__ unsigned short Bs[128 * 32];
    const int t = threadIdx.x;

    const int bi   = blockIdx.x;
    const int xcd  = bi & 7;
    const int j    = bi >> 3;
    const int nby8 = M >> 10;
    const int m_idx = xcd * nby8 + (j >> NBXL);
    const int n_idx = j & ((1 << NBXL) - 1);
    const int n0 = n_idx * 128;
    const int m0 = m_idx * 128;

    const int lane = t & 63;
    const int wave = t >> 6;
    const int wm = (wave >> 1) * 64;
    const int wn = (wave & 1) * 64;
    const int lm = lane & 15;
    const int q  = lane >> 4;

    const int pos0 = wave * 128 + lane;
    const int row0 = pos0 >> 2;
    const int row1 = (pos0 + 64) >> 2;
    const int cg0  = (pos0 & 3) << 3;
    const int ldsb = wave * 1024;

    f32x4 acc[4][4];
#pragma unroll
    for (int i = 0; i < 4; i++)
#pragma unroll
        for (int n = 0; n < 4; n++) acc[i][n] = (f32x4)0.f;

    for (int k0 = 0; k0 < K; k0 += 32) {
        __syncthreads();
        {
            const unsigned short* ga0 = A  + (size_t)(m0 + row0) * K + k0 + cg0;
            const unsigned short* ga1 = A  + (size_t)(m0 + row1) * K + k0 + cg0;
            const unsigned short* gb0 = Bt + (size_t)(n0 + row0) * K + k0 + cg0;
            const unsigned short* gb1 = Bt + (size_t)(n0 + row1) * K + k0 + cg0;
            __builtin_amdgcn_global_load_lds(AS_GLOBAL(ga0), AS_LDS(As + ldsb),       16, 0, 0);
            __builtin_amdgcn_global_load_lds(AS_GLOBAL(ga1), AS_LDS(As + ldsb + 512), 16, 0, 0);
            __builtin_amdgcn_global_load_lds(AS_GLOBAL(gb0), AS_LDS(Bs + ldsb),       16, 0, 0);
            __builtin_amdgcn_global_load_lds(AS_GLOBAL(gb1), AS_LDS(Bs + ldsb + 512), 16, 0, 0);
        }
        __syncthreads();
        bf16x8 af[4], bfr[4];
#pragma unroll
        for (int i = 0; i < 4; i++)
            af[i] = *(const bf16x8*)(As + (wm + i * 16 + lm) * 32 + q * 8);
#pragma unroll
        for (int n = 0; n < 4; n++)
            bfr[n] = *(const bf16x8*)(Bs + (wn + n * 16 + lm) * 32 + q * 8);
#pragma unroll
        for (int i = 0; i < 4; i++)
#pragma unroll
            for (int n = 0; n < 4; n++)
                acc[i][n] = __builtin_amdgcn_mfma_f32_16x16x32_bf16(af[i], bfr[n], acc[i][n], 0, 0, 0);
    }

    const float qsc = (MODE == 5 && n0 < 1024) ? QSCALE : 1.f;
#pragma unroll
    for (int i = 0; i < 4; i++) {
#pragma unroll
        for (int n = 0; n < 4; n++) {
            int gc = n0 + wn + n * 16 + lm;
            float bv = (MODE == 3) ? 0.f : bias[gc];
#pragma unroll
            for (int r = 0; r < 4; r++) {
                int gr = m0 + wm + i * 16 + q * 4 + r;
                float v = acc[i][n][r] + ((MODE == 3) ? bias[gr] : bv);
                if (MODE == 1) {
                    ((unsigned short*)outp)[(size_t)gr * N + gc] = f2b(fast_gelu(v));
                } else if (MODE == 2) {
                    ((float*)outp)[(size_t)gr * N + gc] += v;
                } else if (MODE == 3) {
                    ((unsigned short*)outp)[(size_t)gr * N + gc] = f2b(v);
                } else { // MODE 5
                    ((unsigned short*)outp)[(size_t)gr * N + gc] = f2b(v * qsc);
                }
            }
        }
    }
}

// ---------------- MFMA flash attention v3: 128 q-rows/block, S^T orientation ----------------
// grid = 1024: blk = ((b*16 + h)*8 + qt); 4 waves x 32 q-rows.
// qkb is the fused QK buffer [8192 tokens][2048] (Q cols 0-1023 pre-scaled, K cols 1024-2047).
__global__ __launch_bounds__(256) void attn_k(
    const unsigned short* __restrict__ qkb,
    const unsigned short* __restrict__ vtb,
    float* __restrict__ x)
{
    __shared__ unsigned short SM[18432];
    unsigned short* QP  = SM;            // 128 x 72
    unsigned short* Ks  = SM + 9216;     // 64 x 72
    unsigned short* Vst = SM + 13824;    // 64 x 72
    unsigned short* Ob  = SM + 9216;     // 128 x 72 (aliases Ks+Vst, used after loop)

    const int t    = threadIdx.x;
    const int blk  = blockIdx.x;
    const int qt   = blk & 7;
    const int h    = (blk >> 3) & 15;
    const int b    = blk >> 7;
    const int w    = t >> 6;
    const int lane = t & 63;
    const int l15  = lane & 15;
    const int quad = lane >> 4;
    const int wrow = w * 32;

    // ---- stage Q tile (128 rows x 64 d), pitch 2048 ----
    {
        int r  = t >> 1;
        int dc = (t & 1) << 5;
        const uint4* src = (const uint4*)(qkb + ((size_t)(b * 1024 + qt * 128 + r)) * 2048 + h * 64 + dc);
        uint4 u0 = src[0], u1 = src[1], u2 = src[2], u3 = src[3];
        *(uint4*)(QP + r * 72 + dc)      = u0;
        *(uint4*)(QP + r * 72 + dc + 8)  = u1;
        *(uint4*)(QP + r * 72 + dc + 16) = u2;
        *(uint4*)(QP + r * 72 + dc + 24) = u3;
    }
    __syncthreads();
    bf16x8 qf[2][2];
#pragma unroll
    for (int nt2 = 0; nt2 < 2; nt2++)
#pragma unroll
        for (int kd = 0; kd < 2; kd++)
            qf[nt2][kd] = *(const bf16x8*)(QP + (wrow + nt2 * 16 + l15) * 72 + kd * 32 + quad * 8);

    float m_s[2] = { -1e30f, -1e30f }, l_s[2] = { 0.f, 0.f };
    f32x4 O[2][4];
#pragma unroll
    for (int nt2 = 0; nt2 < 2; nt2++)
#pragma unroll
        for (int dt = 0; dt < 4; dt++) O[nt2][dt] = (f32x4)0.f;

    for (int kt = 0; kt < 16; ++kt) {
        __syncthreads();
        {   // K tile [key][d], from fused buffer cols 1024+
            int r  = t >> 2;
            int dc = (t & 3) << 4;
            const uint4* src = (const uint4*)(qkb + ((size_t)(b * 1024 + kt * 64 + r)) * 2048 + 1024 + h * 64 + dc);
            uint4 u0 = src[0], u1 = src[1];
            *(uint4*)(Ks + r * 72 + dc)     = u0;
            *(uint4*)(Ks + r * 72 + dc + 8) = u1;
        }
        {   // V^T tile [d][key]
            int d  = t >> 2;
            int kc = (t & 3) << 4;
            const uint4* src = (const uint4*)(vtb + (size_t)(h * 64 + d) * 8192 + b * 1024 + kt * 64 + kc);
            uint4 u0 = src[0], u1 = src[1];
            *(uint4*)(Vst + d * 72 + kc)     = u0;
            *(uint4*)(Vst + d * 72 + kc + 8) = u1;
        }
        __syncthreads();

        // ---- S^T = K Q^T ----
        f32x4 s[4][2];
#pragma unroll
        for (int mt = 0; mt < 4; mt++) {
            bf16x8 kf0 = *(const bf16x8*)(Ks + (mt * 16 + l15) * 72 + quad * 8);
            bf16x8 kf1 = *(const bf16x8*)(Ks + (mt * 16 + l15) * 72 + 32 + quad * 8);
#pragma unroll
            for (int nt2 = 0; nt2 < 2; nt2++) {
                f32x4 a = (f32x4)0.f;
                a = __builtin_amdgcn_mfma_f32_16x16x32_bf16(kf0, qf[nt2][0], a, 0, 0, 0);
                a = __builtin_amdgcn_mfma_f32_16x16x32_bf16(kf1, qf[nt2][1], a, 0, 0, 0);
                s[mt][nt2] = a;
            }
        }

        // ---- online softmax (exp2 domain) ----
#pragma unroll
        for (int nt2 = 0; nt2 < 2; nt2++) {
            float tm = -1e30f;
#pragma unroll
            for (int mt = 0; mt < 4; mt++) {
                f32x4 sv = s[mt][nt2];
                tm = fmaxf(tm, fmaxf(fmaxf(sv[0], sv[1]), fmaxf(sv[2], sv[3])));
            }
            tm = fmaxf(tm, __shfl_xor(tm, 16));
            tm = fmaxf(tm, __shfl_xor(tm, 32));
            float nm    = fmaxf(m_s[nt2], tm);
            float alpha = exp2f(m_s[nt2] - nm);
            float ls = 0.f;
#pragma unroll
            for (int mt = 0; mt < 4; mt++) {
#pragma unroll
                for (int r = 0; r < 4; r++) {
                    float p = exp2f(s[mt][nt2][r] - nm);
                    s[mt][nt2][r] = p;
                    ls += p;
                }
            }
            ls += __shfl_xor(ls, 16);
            ls += __shfl_xor(ls, 32);
            l_s[nt2] = l_s[nt2] * alpha + ls;
            m_s[nt2] = nm;
#pragma unroll
            for (int dt = 0; dt < 4; dt++) O[nt2][dt] *= alpha;
        }

        // ---- P^T -> LDS [qrow][key] ----
#pragma unroll
        for (int nt2 = 0; nt2 < 2; nt2++) {
#pragma unroll
            for (int mt = 0; mt < 4; mt++) {
                uint2 pk = pk4(s[mt][nt2][0], s[mt][nt2][1], s[mt][nt2][2], s[mt][nt2][3]);
                *(uint2*)(QP + (wrow + nt2 * 16 + l15) * 72 + mt * 16 + quad * 4) = pk;
            }
        }
        bf16x8 pf[2][2];
#pragma unroll
        for (int nt2 = 0; nt2 < 2; nt2++)
#pragma unroll
            for (int kc = 0; kc < 2; kc++)
                pf[nt2][kc] = *(const bf16x8*)(QP + (wrow + nt2 * 16 + l15) * 72 + kc * 32 + quad * 8);

        // ---- O^T += V^T P^T ----
#pragma unroll
        for (int dt = 0; dt < 4; dt++) {
            bf16x8 vf0 = *(const bf16x8*)(Vst + (dt * 16 + l15) * 72 + quad * 8);
            bf16x8 vf1 = *(const bf16x8*)(Vst + (dt * 16 + l15) * 72 + 32 + quad * 8);
#pragma unroll
            for (int nt2 = 0; nt2 < 2; nt2++) {
                O[nt2][dt] = __builtin_amdgcn_mfma_f32_16x16x32_bf16(vf0, pf[nt2][0], O[nt2][dt], 0, 0, 0);
                O[nt2][dt] = __builtin_amdgcn_mfma_f32_16x16x32_bf16(vf1, pf[nt2][1], O[nt2][dt], 0, 0, 0);
            }
        }
    }

    // ---- O^T -> LDS (bf16); coalesced residual add ----
    __syncthreads();
    {
        float inv0 = 1.f / l_s[0], inv1 = 1.f / l_s[1];
#pragma unroll
        for (int nt2 = 0; nt2 < 2; nt2++) {
            float inv = (nt2 == 0) ? inv0 : inv1;
#pragma unroll
            for (int dt = 0; dt < 4; dt++) {
                uint2 pk = pk4(O[nt2][dt][0] * inv, O[nt2][dt][1] * inv,
                               O[nt2][dt][2] * inv, O[nt2][dt][3] * inv);
                *(uint2*)(Ob + (wrow + nt2 * 16 + l15) * 72 + dt * 16 + quad * 4) = pk;
            }
        }
    }
    __syncthreads();
    {
        int r0 = t >> 2;
        int qo = (t & 3) << 4;
#pragma unroll
        for (int half = 0; half < 2; half++) {
            int r = r0 + half * 64;
            float* xp = x + ((size_t)(b * 1024 + qt * 128 + r)) * 1024 + h * 64 + qo;
            const unsigned short* op = Ob + r * 72 + qo;
#pragma unroll
            for (int j = 0; j < 2; j++) {
                uint4 u = *(const uint4*)(op + j * 8);
                f32x4 xv0 = *(f32x4*)(xp + j * 8);
                f32x4 xv1 = *(f32x4*)(xp + j * 8 + 4);
                xv0[0] += b2f((unsigned short)(u.x & 0xffff));
                xv0[1] += b2f((unsigned short)(u.x >> 16));
                xv0[2] += b2f((unsigned short)(u.y & 0xffff));
                xv0[3] += b2f((unsigned short)(u.y >> 16));
                xv1[0] += b2f((unsigned short)(u.z & 0xffff));
                xv1[1] += b2f((unsigned short)(u.z >> 16));
                xv1[2] += b2f((unsigned short)(u.w & 0xffff));
                xv1[3] += b2f((unsigned short)(u.w >> 16));
                *(f32x4*)(xp + j * 8)     = xv0;
                *(f32x4*)(xp + j * 8 + 4) = xv1;
            }
        }
    }
}

// ---------------- launch ----------------
extern "C" void kernel_launch(void* const* d_in, const int* in_sizes, int n_in,
                              void* d_out, int out_size, void* d_ws, size_t ws_size,
                              hipStream_t stream)
{
    (void)in_sizes; (void)n_in; (void)out_size; (void)ws_size;
    const float* x_in  = (const float*)d_in[0];
    const float* Wq    = (const float*)d_in[1];
    const float* bq    = (const float*)d_in[2];
    const float* Wk    = (const float*)d_in[3];
    const float* bk    = (const float*)d_in[4];
    const float* Wv    = (const float*)d_in[5];
    const float* bv    = (const float*)d_in[6];
    const float* W1    = (const float*)d_in[7];
    const float* b1    = (const float*)d_in[8];
    const float* W2    = (const float*)d_in[9];
    const float* b2    = (const float*)d_in[10];
    const float* gamma = (const float*)d_in[11];
    const float* beta  = (const float*)d_in[12];

    char* base = (char*)d_ws;
    float*          xf   = (float*)(base);                                // 32 MB
    unsigned short* xn   = (unsigned short*)(base + 33554432);            // 16 MB
    unsigned short* qkb  = (unsigned short*)(base + 50331648);            // 32 MB fused QK [8192][2048]
    unsigned short* vtb  = (unsigned short*)(base + 50331648 + 33554432); // 16 MB V^T [1024][8192]
    unsigned short* h1   = (unsigned short*)(base + 50331648);            // 64 MB (aliases qk/vt)
    char* wbase = base + 50331648 + 67108864;
    unsigned short* WqkT = (unsigned short*)(wbase);                      // 4 MB fused [2048][1024]
    unsigned short* WvT  = (unsigned short*)(wbase + 4194304);
    unsigned short* W1T  = (unsigned short*)(wbase + 6291456);
    unsigned short* W2T  = (unsigned short*)(wbase + 14680064);
    float*          bqk  = (float*)(wbase + 23068672);                    // 8 KB

    transpose_f32_to_bf16<<<dim3(32, 32),  256, 0, stream>>>(Wq, WqkT, 1024, 1024);
    transpose_f32_to_bf16<<<dim3(32, 32),  256, 0, stream>>>(Wk, WqkT + 1048576, 1024, 1024);
    transpose_f32_to_bf16<<<dim3(32, 32),  256, 0, stream>>>(Wv, WvT, 1024, 1024);
    transpose_f32_to_bf16<<<dim3(128, 32), 256, 0, stream>>>(W1, W1T, 1024, 4096);
    transpose_f32_to_bf16<<<dim3(32, 128), 256, 0, stream>>>(W2, W2T, 4096, 1024);
    concat_bias<<<8, 256, 0, stream>>>(bq, bk, bqk);
    copy_f32<<<4096, 256, 0, stream>>>(x_in, xf);

    for (int layer = 0; layer < 6; ++layer) {
        layernorm_k<<<8192, 256, 0, stream>>>(xf, gamma, beta, xn);
        // fused QK: M=8192 N=2048 (nbx=16, NBXL=4), 1024 blocks
        gemm_bt<5, 4><<<1024, 256, 0, stream>>>(xn, WqkT, bqk, qkb, 8192, 2048, 1024);
        // V^T: M=1024 N=8192 (nbx=64, NBXL=6), 512 blocks
        gemm_bt<3, 6><<<512,  256, 0, stream>>>(WvT, xn, bv, vtb, 1024, 8192, 1024);
        attn_k<<<1024, 256, 0, stream>>>(qkb, vtb, xf);
        layernorm_k<<<8192, 256, 0, stream>>>(xf, gamma, beta, xn);
        // MLP up: M=8192 N=4096 (nbx=32, NBXL=5), 2048 blocks
        gemm_bt<1, 5><<<2048, 256, 0, stream>>>(xn, W1T, b1, h1, 8192, 4096, 1024);
        // MLP down: M=8192 N=1024 (nbx=8, NBXL=3), 512 blocks
        gemm_bt<2, 3><<<512,  256, 0, stream>>>(h1, W2T, b2, xf, 8192, 1024, 4096);
    }
    copy_f32<<<4096, 256, 0, stream>>>(xf, (float*)d_out);
}